// Round 4
// baseline (293.071 us; speedup 1.0000x reference)
//
#include <hip/hip_runtime.h>
#include <hip/hip_bf16.h>
#include <hip/hip_cooperative_groups.h>
#include <stdint.h>

namespace cg = cooperative_groups;

#define NB 64
#define NC 512
#define NHW 784
#define NK 49
#define KP 64
#define NR 32
#define NTASK 10
#define MGRID 512

typedef short sh8 __attribute__((ext_vector_type(8)));
typedef float f32x4 __attribute__((ext_vector_type(4)));
typedef int v4i __attribute__((ext_vector_type(4)));

__device__ __forceinline__ float wave_sum(float v) {
#pragma unroll
  for (int o = 32; o; o >>= 1) v += __shfl_xor(v, o);
  return v;
}

__device__ __forceinline__ void task_decode(int s, int& ti, int& tj) {
  // upper-triangle enumeration: (0,0)(0,1)(0,2)(0,3)(1,1)(1,2)(1,3)(2,2)(2,3)(3,3)
  if (s < 4) { ti = 0; tj = s; }
  else if (s < 7) { ti = 1; tj = s - 3; }
  else if (s < 9) { ti = 2; tj = s - 5; }
  else { ti = 3; tj = 3; }
}

// =======================================================================
// MEGA cooperative kernel: pool -> dsum -> sim -> mlp -> scale, 4 grid syncs
// =======================================================================
__global__ __launch_bounds__(256, 2) void mega_kernel(
    const float* __restrict__ x, __hip_bfloat16* __restrict__ xap,
    float* __restrict__ wbuf, float* __restrict__ gap, float* __restrict__ dpart,
    float* __restrict__ spart, float* __restrict__ tpart, float* __restrict__ scl,
    const float* __restrict__ wD, const float* __restrict__ bD,
    const float* __restrict__ wU, const float* __restrict__ bU, float* __restrict__ out) {
  cg::grid_group grid = cg::this_grid();
  __shared__ __align__(16) __hip_bfloat16 Ab[128 * KP];
  __shared__ __align__(16) __hip_bfloat16 Bb[128 * KP];
  __shared__ float wiL[128], wjL[128], zL[NC], tfull[NC];
  __shared__ float red[4];
  __shared__ float hL[NR];
  int t = threadIdx.x;
  int lane = t & 63, wave = t >> 6;
  int blk = blockIdx.x;

  // ---------------- phase 0: pool (each wave = one row; 16 iterations) ----------------
#pragma unroll 2
  for (int it = 0; it < 16; ++it) {
    int row = (it * MGRID + blk) * 4 + wave;  // b*512 + c, < 32768
    const float* xr = x + (size_t)row * NHW;
    float bin = 0.f;
    if (lane < NK) {
      int pr = lane / 7, pc = lane - pr * 7;
      const float4* p = (const float4*)(xr + pr * 112 + pc * 4);
      float s = 0.f;
#pragma unroll
      for (int i = 0; i < 4; ++i) {
        float4 v = p[i * 7];
        s += (v.x + v.y) + (v.z + v.w);
      }
      bin = s * 0.0625f;
    }
    float s1 = wave_sum(bin);
    float s2 = wave_sum(bin * bin);
    xap[(size_t)row * KP + lane] = __float2bfloat16(bin);
    if (lane == 0) {
      wbuf[row] = sqrtf(s2);
      gap[row] = s1 * (1.f / 49.f);
    }
  }
  grid.sync();

  // ---------------- phase 1: d-sums over triangle tiles ----------------
  for (int task = blk; task < NB * NTASK; task += MGRID) {
    int b = task / NTASK, s = task - b * NTASK;
    int ti, tj;
    task_decode(s, ti, tj);
    bool diag = (ti == tj);
    int i0 = ti * 128, j0 = tj * 128;
    const v4i* ga = (const v4i*)(xap + ((size_t)b * NC + i0) * KP);
    const v4i* gb = (const v4i*)(xap + ((size_t)b * NC + j0) * KP);
    v4i* la = (v4i*)Ab;
    v4i* lb = (v4i*)Bb;
    __syncthreads();  // LDS reuse guard
#pragma unroll
    for (int q = 0; q < 4; ++q) {
      int cid = q * 256 + t;
      int r = cid >> 3, c = cid & 7;
      int dst = (r << 3) | (c ^ (r & 7));
      la[dst] = ga[cid];
      lb[dst] = gb[cid];
    }
    if (t < 128) {
      wiL[t] = wbuf[b * NC + i0 + t];
      wjL[t] = wbuf[b * NC + j0 + t];
    }
    __syncthreads();
    int wi = wave >> 1, wn = wave & 1;
    int l15 = lane & 15, g16 = lane >> 4;
    sh8 af[4][2], bfr[4][2];
#pragma unroll
    for (int f = 0; f < 4; ++f) {
#pragma unroll
      for (int ks = 0; ks < 2; ++ks) {
        int ra = wi * 64 + f * 16 + l15;
        int rb = wn * 64 + f * 16 + l15;
        int cg2 = ks * 4 + g16;
        af[f][ks] = __builtin_bit_cast(sh8, ((const v4i*)Ab)[(ra << 3) | (cg2 ^ (ra & 7))]);
        bfr[f][ks] = __builtin_bit_cast(sh8, ((const v4i*)Bb)[(rb << 3) | (cg2 ^ (rb & 7))]);
      }
    }
    f32x4 acc[4][4];
#pragma unroll
    for (int fm = 0; fm < 4; ++fm)
#pragma unroll
      for (int fn = 0; fn < 4; ++fn) acc[fm][fn] = (f32x4){0.f, 0.f, 0.f, 0.f};
#pragma unroll
    for (int ks = 0; ks < 2; ++ks)
#pragma unroll
      for (int fm = 0; fm < 4; ++fm)
#pragma unroll
        for (int fn = 0; fn < 4; ++fn)
          acc[fm][fn] = __builtin_amdgcn_mfma_f32_16x16x32_bf16(af[fm][ks], bfr[fn][ks],
                                                                acc[fm][fn], 0, 0, 0);
    float a2[4][4], b2[4];
#pragma unroll
    for (int fm = 0; fm < 4; ++fm)
#pragma unroll
      for (int rg = 0; rg < 4; ++rg) {
        float a = wiL[wi * 64 + fm * 16 + g16 * 4 + rg];
        a2[fm][rg] = a * a;
      }
#pragma unroll
    for (int fn = 0; fn < 4; ++fn) {
      float w = wjL[wn * 64 + fn * 16 + l15];
      b2[fn] = w * w;
    }
    float dsum = 0.f;
#pragma unroll
    for (int fm = 0; fm < 4; ++fm)
#pragma unroll
      for (int fn = 0; fn < 4; ++fn)
#pragma unroll
        for (int rg = 0; rg < 4; ++rg) {
          float d2 = fmaf(-2.f, acc[fm][fn][rg], a2[fm][rg] + b2[fn]);
          dsum += sqrtf(fmaxf(d2, 0.f));
        }
    dsum = wave_sum(dsum);
    if (lane == 0) red[wave] = dsum;
    __syncthreads();
    if (t == 0) dpart[task] = ((red[0] + red[1]) + (red[2] + red[3])) * (diag ? 1.f : 2.f);
  }
  grid.sync();

  // ---------------- phase 2: sim over triangle tiles ----------------
  for (int task = blk; task < NB * NTASK; task += MGRID) {
    int b = task / NTASK, s = task - b * NTASK;
    int ti, tj;
    task_decode(s, ti, tj);
    bool diag = (ti == tj);
    int i0 = ti * 128, j0 = tj * 128;
    float dsb = 0.f;
#pragma unroll
    for (int k = 0; k < NTASK; ++k) dsb += dpart[b * NTASK + k];
    float nim = -1.44269504f / (dsb * (1.f / 262144.f) + 1e-10f);  // -log2e / mean_d
    const v4i* ga = (const v4i*)(xap + ((size_t)b * NC + i0) * KP);
    const v4i* gb = (const v4i*)(xap + ((size_t)b * NC + j0) * KP);
    v4i* la = (v4i*)Ab;
    v4i* lb = (v4i*)Bb;
    __syncthreads();  // LDS reuse guard
#pragma unroll
    for (int q = 0; q < 4; ++q) {
      int cid = q * 256 + t;
      int r = cid >> 3, c = cid & 7;
      int dst = (r << 3) | (c ^ (r & 7));
      la[dst] = ga[cid];
      lb[dst] = gb[cid];
    }
    if (t < 128) {
      wiL[t] = wbuf[b * NC + i0 + t];
      wjL[t] = wbuf[b * NC + j0 + t];
    }
    tfull[t] = 0.f;
    tfull[t + 256] = 0.f;
    // z = (gap - mu)/std, bitwise identical wherever recomputed
    float g0 = gap[b * NC + t], g1 = gap[b * NC + t + 256];
    float s1 = wave_sum(g0 + g1);
    if (lane == 0) red[wave] = s1;
    __syncthreads();
    float mu = ((red[0] + red[1]) + (red[2] + red[3])) * (1.f / 512.f);
    float e0 = g0 - mu, e1 = g1 - mu;
    __syncthreads();
    float vv = wave_sum(e0 * e0 + e1 * e1);
    if (lane == 0) red[wave] = vv;
    __syncthreads();
    float inv_sd = 1.f / sqrtf(((red[0] + red[1]) + (red[2] + red[3])) * (1.f / 511.f));
    zL[t] = e0 * inv_sd;
    zL[t + 256] = e1 * inv_sd;
    __syncthreads();
    int wi = wave >> 1, wn = wave & 1;
    int l15 = lane & 15, g16 = lane >> 4;
    sh8 af[4][2], bfr[4][2];
#pragma unroll
    for (int f = 0; f < 4; ++f) {
#pragma unroll
      for (int ks = 0; ks < 2; ++ks) {
        int ra = wi * 64 + f * 16 + l15;
        int rb = wn * 64 + f * 16 + l15;
        int cg2 = ks * 4 + g16;
        af[f][ks] = __builtin_bit_cast(sh8, ((const v4i*)Ab)[(ra << 3) | (cg2 ^ (ra & 7))]);
        bfr[f][ks] = __builtin_bit_cast(sh8, ((const v4i*)Bb)[(rb << 3) | (cg2 ^ (rb & 7))]);
      }
    }
    f32x4 acc[4][4];
#pragma unroll
    for (int fm = 0; fm < 4; ++fm)
#pragma unroll
      for (int fn = 0; fn < 4; ++fn) acc[fm][fn] = (f32x4){0.f, 0.f, 0.f, 0.f};
#pragma unroll
    for (int ks = 0; ks < 2; ++ks)
#pragma unroll
      for (int fm = 0; fm < 4; ++fm)
#pragma unroll
        for (int fn = 0; fn < 4; ++fn)
          acc[fm][fn] = __builtin_amdgcn_mfma_f32_16x16x32_bf16(af[fm][ks], bfr[fn][ks],
                                                                acc[fm][fn], 0, 0, 0);
    float a2[4][4], ia[4][4], zi[4][4];
#pragma unroll
    for (int fm = 0; fm < 4; ++fm)
#pragma unroll
      for (int rg = 0; rg < 4; ++rg) {
        int il = wi * 64 + fm * 16 + g16 * 4 + rg;
        float a = wiL[il];
        a2[fm][rg] = a * a;
        ia[fm][rg] = 1.f / fmaxf(a, 1e-7f);
        zi[fm][rg] = zL[i0 + il];
      }
    float b2[4], ib[4], zj[4];
#pragma unroll
    for (int fn = 0; fn < 4; ++fn) {
      int jl = wn * 64 + fn * 16 + l15;
      float w = wjL[jl];
      b2[fn] = w * w;
      ib[fn] = 1.f / fmaxf(w, 1e-7f);
      zj[fn] = zL[j0 + jl];
    }
    float ssum = 0.f;
    float trow[4][4];
    float tcol[4] = {0.f, 0.f, 0.f, 0.f};
#pragma unroll
    for (int fm = 0; fm < 4; ++fm)
#pragma unroll
      for (int rg = 0; rg < 4; ++rg) trow[fm][rg] = 0.f;
#pragma unroll
    for (int fm = 0; fm < 4; ++fm)
#pragma unroll
      for (int fn = 0; fn < 4; ++fn) {
        float ibn = ib[fn];
#pragma unroll
        for (int rg = 0; rg < 4; ++rg) {
          float g = acc[fm][fn][rg];
          float d2 = fmaf(-2.f, g, a2[fm][rg] + b2[fn]);
          float d = sqrtf(fmaxf(d2, 0.f));
          float sim = fmaxf(g, 0.f) * ia[fm][rg] * ibn * exp2f(d * nim);
          if (diag) {
            int il = wi * 64 + fm * 16 + g16 * 4 + rg;
            int jl = wn * 64 + fn * 16 + l15;
            if (il == jl) sim = 0.f;
          }
          ssum += sim;
          trow[fm][rg] = fmaf(sim, zj[fn], trow[fm][rg]);
          tcol[fn] = fmaf(sim, zi[fm][rg], tcol[fn]);
        }
      }
#pragma unroll
    for (int fm = 0; fm < 4; ++fm)
#pragma unroll
      for (int rg = 0; rg < 4; ++rg) {
        float v = trow[fm][rg];
#pragma unroll
        for (int o = 8; o; o >>= 1) v += __shfl_xor(v, o);
        if (l15 == 0) atomicAdd(&tfull[i0 + wi * 64 + fm * 16 + g16 * 4 + rg], v);
      }
    if (!diag) {
#pragma unroll
      for (int fn = 0; fn < 4; ++fn) {
        float v = tcol[fn];
        v += __shfl_xor(v, 16);
        v += __shfl_xor(v, 32);
        if (g16 == 0) atomicAdd(&tfull[j0 + wn * 64 + fn * 16 + l15], v);
      }
    }
    ssum = wave_sum(ssum);
    if (lane == 0) red[wave] = ssum;
    __syncthreads();
    if (t == 0) spart[task] = ((red[0] + red[1]) + (red[2] + red[3])) * (diag ? 1.f : 2.f);
    tpart[(size_t)task * NC + t] = tfull[t];
    tpart[(size_t)task * NC + t + 256] = tfull[t + 256];
  }
  grid.sync();

  // ---------------- phase 3: MLP (blocks 0..63, one batch each) ----------------
  if (blk < NB) {
    int b = blk;
    float* chL = tfull;  // reuse
    __syncthreads();
    float S = 0.f;
#pragma unroll
    for (int k = 0; k < NTASK; ++k) S += spart[b * NTASK + k];
    float invS = 1.f / (S + 1e-10f);
    float t0 = 0.f, t1 = 0.f;
#pragma unroll
    for (int j = 0; j < NTASK; ++j) {
      t0 += tpart[((size_t)b * NTASK + j) * NC + t];
      t1 += tpart[((size_t)b * NTASK + j) * NC + t + 256];
    }
    float g0 = gap[b * NC + t], g1 = gap[b * NC + t + 256];
    float s1 = wave_sum(g0 + g1);
    if (lane == 0) red[wave] = s1;
    __syncthreads();
    float mu = ((red[0] + red[1]) + (red[2] + red[3])) * (1.f / 512.f);
    float e0 = g0 - mu, e1 = g1 - mu;
    __syncthreads();
    float vv = wave_sum(e0 * e0 + e1 * e1);
    if (lane == 0) red[wave] = vv;
    __syncthreads();
    float inv_sd = 1.f / sqrtf(((red[0] + red[1]) + (red[2] + red[3])) * (1.f / 511.f));
    float lm0 = e0 * inv_sd * t0 * invS;
    float lm1 = e1 * inv_sd * t1 * invS;
    __syncthreads();
    float s2 = wave_sum(lm0 + lm1);
    if (lane == 0) red[wave] = s2;
    __syncthreads();
    float m = ((red[0] + red[1]) + (red[2] + red[3])) * (1.f / 512.f);
    float d0 = lm0 - m, d1 = lm1 - m;
    __syncthreads();
    float v2 = wave_sum(d0 * d0 + d1 * d1);
    if (lane == 0) red[wave] = v2;
    __syncthreads();
    float sd = sqrtf(((red[0] + red[1]) + (red[2] + red[3])) * (1.f / 511.f)) + 1e-12f;
    chL[t] = d0 / sd;
    chL[t + 256] = d1 / sd;
    __syncthreads();
    int k = t >> 3, p = t & 7;
    const float* wrow = wD + k * NC + p * 64;
    const float* cp = chL + p * 64;
    float hp = 0.f;
#pragma unroll
    for (int i = 0; i < 64; ++i) hp += wrow[i] * cp[i];
#pragma unroll
    for (int o = 4; o; o >>= 1) hp += __shfl_xor(hp, o);
    if (p == 0) hL[k] = fmaxf(hp + bD[k], 0.f);
    __syncthreads();
#pragma unroll
    for (int u = 0; u < 2; ++u) {
      int c = t + u * 256;
      const float* wrU = wU + c * NR;
      float att = bU[c];
#pragma unroll
      for (int kk = 0; kk < NR; ++kk) att += hL[kk] * wrU[kk];
      scl[b * NC + c] = 1.f / (1.f + __expf(-att));
    }
  }
  grid.sync();

  // ---------------- phase 4: out = x * scale (49 exact iterations) ----------------
  {
    const f32x4* xv = (const f32x4*)x;
    f32x4* ov = (f32x4*)out;
    int base = blk * 256 + t;  // 0..131071
#pragma unroll 7
    for (int i = 0; i < 49; ++i) {
      int idx = i * (MGRID * 256) + base;
      unsigned row = (unsigned)idx / 196u;
      f32x4 v = xv[idx];
      v *= scl[row];
      __builtin_nontemporal_store(v, ov + idx);
    }
  }
}

// =======================================================================
// Fallback classic path (5 kernels) — used if cooperative launch fails
// =======================================================================
__global__ __launch_bounds__(256) void pool_kernel(const float* __restrict__ x,
                                                   __hip_bfloat16* __restrict__ xap,
                                                   float* __restrict__ wbuf,
                                                   float* __restrict__ gap) {
  int wid = threadIdx.x >> 6, lane = threadIdx.x & 63;
  int row = blockIdx.x * 4 + wid;
  const float* xr = x + (size_t)row * NHW;
  float bin = 0.f;
  if (lane < NK) {
    int pr = lane / 7, pc = lane - pr * 7;
    const float4* p = (const float4*)(xr + pr * 112 + pc * 4);
    float s = 0.f;
#pragma unroll
    for (int i = 0; i < 4; ++i) {
      float4 v = p[i * 7];
      s += (v.x + v.y) + (v.z + v.w);
    }
    bin = s * 0.0625f;
  }
  float s1 = wave_sum(bin);
  float s2 = wave_sum(bin * bin);
  xap[(size_t)row * KP + lane] = __float2bfloat16(bin);
  if (lane == 0) {
    wbuf[row] = sqrtf(s2);
    gap[row] = s1 * (1.f / 49.f);
  }
}

__global__ __launch_bounds__(256) void meand_kernel(const __hip_bfloat16* __restrict__ xap,
                                                    const float* __restrict__ wbuf,
                                                    float* __restrict__ dpart) {
  __shared__ __align__(16) __hip_bfloat16 Ab[128 * KP];
  __shared__ __align__(16) __hip_bfloat16 Bb[128 * KP];
  __shared__ float wiL[128], wjL[128];
  __shared__ float red[4];
  int blk = blockIdx.x;
  int b = blk / NTASK, s = blk - b * NTASK;
  int ti, tj;
  task_decode(s, ti, tj);
  bool diag = (ti == tj);
  int i0 = ti * 128, j0 = tj * 128;
  int t = threadIdx.x;
  const v4i* ga = (const v4i*)(xap + ((size_t)b * NC + i0) * KP);
  const v4i* gb = (const v4i*)(xap + ((size_t)b * NC + j0) * KP);
  v4i* la = (v4i*)Ab;
  v4i* lb = (v4i*)Bb;
#pragma unroll
  for (int q = 0; q < 4; ++q) {
    int cid = q * 256 + t;
    int r = cid >> 3, c = cid & 7;
    int dst = (r << 3) | (c ^ (r & 7));
    la[dst] = ga[cid];
    lb[dst] = gb[cid];
  }
  if (t < 128) {
    wiL[t] = wbuf[b * NC + i0 + t];
    wjL[t] = wbuf[b * NC + j0 + t];
  }
  __syncthreads();
  int lane = t & 63, wave = t >> 6;
  int wi = wave >> 1, wn = wave & 1;
  int l15 = lane & 15, g16 = lane >> 4;
  sh8 af[4][2], bfr[4][2];
#pragma unroll
  for (int f = 0; f < 4; ++f) {
#pragma unroll
    for (int ks = 0; ks < 2; ++ks) {
      int ra = wi * 64 + f * 16 + l15;
      int rb = wn * 64 + f * 16 + l15;
      int cg2 = ks * 4 + g16;
      af[f][ks] = __builtin_bit_cast(sh8, ((const v4i*)Ab)[(ra << 3) | (cg2 ^ (ra & 7))]);
      bfr[f][ks] = __builtin_bit_cast(sh8, ((const v4i*)Bb)[(rb << 3) | (cg2 ^ (rb & 7))]);
    }
  }
  f32x4 acc[4][4];
#pragma unroll
  for (int fm = 0; fm < 4; ++fm)
#pragma unroll
    for (int fn = 0; fn < 4; ++fn) acc[fm][fn] = (f32x4){0.f, 0.f, 0.f, 0.f};
#pragma unroll
  for (int ks = 0; ks < 2; ++ks)
#pragma unroll
    for (int fm = 0; fm < 4; ++fm)
#pragma unroll
      for (int fn = 0; fn < 4; ++fn)
        acc[fm][fn] =
            __builtin_amdgcn_mfma_f32_16x16x32_bf16(af[fm][ks], bfr[fn][ks], acc[fm][fn], 0, 0, 0);
  float a2[4][4], b2[4];
#pragma unroll
  for (int fm = 0; fm < 4; ++fm)
#pragma unroll
    for (int rg = 0; rg < 4; ++rg) {
      float a = wiL[wi * 64 + fm * 16 + g16 * 4 + rg];
      a2[fm][rg] = a * a;
    }
#pragma unroll
  for (int fn = 0; fn < 4; ++fn) {
    float w = wjL[wn * 64 + fn * 16 + l15];
    b2[fn] = w * w;
  }
  float dsum = 0.f;
#pragma unroll
  for (int fm = 0; fm < 4; ++fm)
#pragma unroll
    for (int fn = 0; fn < 4; ++fn)
#pragma unroll
      for (int rg = 0; rg < 4; ++rg) {
        float d2 = fmaf(-2.f, acc[fm][fn][rg], a2[fm][rg] + b2[fn]);
        dsum += sqrtf(fmaxf(d2, 0.f));
      }
  dsum = wave_sum(dsum);
  if (lane == 0) red[wave] = dsum;
  __syncthreads();
  if (t == 0) dpart[blk] = ((red[0] + red[1]) + (red[2] + red[3])) * (diag ? 1.f : 2.f);
}

__global__ __launch_bounds__(256) void sim_kernel(const __hip_bfloat16* __restrict__ xap,
                                                  const float* __restrict__ wbuf,
                                                  const float* __restrict__ gap,
                                                  const float* __restrict__ dpart,
                                                  float* __restrict__ tpart,
                                                  float* __restrict__ spart) {
  __shared__ __align__(16) __hip_bfloat16 Ab[128 * KP];
  __shared__ __align__(16) __hip_bfloat16 Bb[128 * KP];
  __shared__ float wiL[128], wjL[128], zL[NC], tfull[NC];
  __shared__ float red[4];
  int blk = blockIdx.x;
  int b = blk / NTASK, s = blk - b * NTASK;
  int ti, tj;
  task_decode(s, ti, tj);
  bool diag = (ti == tj);
  int i0 = ti * 128, j0 = tj * 128;
  int t = threadIdx.x;
  int lane = t & 63, wave = t >> 6;
  float dsb = 0.f;
#pragma unroll
  for (int k = 0; k < NTASK; ++k) dsb += dpart[b * NTASK + k];
  float nim = -1.44269504f / (dsb * (1.f / 262144.f) + 1e-10f);
  const v4i* ga = (const v4i*)(xap + ((size_t)b * NC + i0) * KP);
  const v4i* gb = (const v4i*)(xap + ((size_t)b * NC + j0) * KP);
  v4i* la = (v4i*)Ab;
  v4i* lb = (v4i*)Bb;
#pragma unroll
  for (int q = 0; q < 4; ++q) {
    int cid = q * 256 + t;
    int r = cid >> 3, c = cid & 7;
    int dst = (r << 3) | (c ^ (r & 7));
    la[dst] = ga[cid];
    lb[dst] = gb[cid];
  }
  if (t < 128) {
    wiL[t] = wbuf[b * NC + i0 + t];
    wjL[t] = wbuf[b * NC + j0 + t];
  }
  tfull[t] = 0.f;
  tfull[t + 256] = 0.f;
  float g0 = gap[b * NC + t], g1 = gap[b * NC + t + 256];
  float s1 = wave_sum(g0 + g1);
  if (lane == 0) red[wave] = s1;
  __syncthreads();
  float mu = ((red[0] + red[1]) + (red[2] + red[3])) * (1.f / 512.f);
  float e0 = g0 - mu, e1 = g1 - mu;
  __syncthreads();
  float vv = wave_sum(e0 * e0 + e1 * e1);
  if (lane == 0) red[wave] = vv;
  __syncthreads();
  float inv_sd = 1.f / sqrtf(((red[0] + red[1]) + (red[2] + red[3])) * (1.f / 511.f));
  zL[t] = e0 * inv_sd;
  zL[t + 256] = e1 * inv_sd;
  __syncthreads();
  int wi = wave >> 1, wn = wave & 1;
  int l15 = lane & 15, g16 = lane >> 4;
  sh8 af[4][2], bfr[4][2];
#pragma unroll
  for (int f = 0; f < 4; ++f) {
#pragma unroll
    for (int ks = 0; ks < 2; ++ks) {
      int ra = wi * 64 + f * 16 + l15;
      int rb = wn * 64 + f * 16 + l15;
      int cg2 = ks * 4 + g16;
      af[f][ks] = __builtin_bit_cast(sh8, ((const v4i*)Ab)[(ra << 3) | (cg2 ^ (ra & 7))]);
      bfr[f][ks] = __builtin_bit_cast(sh8, ((const v4i*)Bb)[(rb << 3) | (cg2 ^ (rb & 7))]);
    }
  }
  f32x4 acc[4][4];
#pragma unroll
  for (int fm = 0; fm < 4; ++fm)
#pragma unroll
    for (int fn = 0; fn < 4; ++fn) acc[fm][fn] = (f32x4){0.f, 0.f, 0.f, 0.f};
#pragma unroll
  for (int ks = 0; ks < 2; ++ks)
#pragma unroll
    for (int fm = 0; fm < 4; ++fm)
#pragma unroll
      for (int fn = 0; fn < 4; ++fn)
        acc[fm][fn] =
            __builtin_amdgcn_mfma_f32_16x16x32_bf16(af[fm][ks], bfr[fn][ks], acc[fm][fn], 0, 0, 0);
  float a2[4][4], ia[4][4], zi[4][4];
#pragma unroll
  for (int fm = 0; fm < 4; ++fm)
#pragma unroll
    for (int rg = 0; rg < 4; ++rg) {
      int il = wi * 64 + fm * 16 + g16 * 4 + rg;
      float a = wiL[il];
      a2[fm][rg] = a * a;
      ia[fm][rg] = 1.f / fmaxf(a, 1e-7f);
      zi[fm][rg] = zL[i0 + il];
    }
  float b2[4], ib[4], zj[4];
#pragma unroll
  for (int fn = 0; fn < 4; ++fn) {
    int jl = wn * 64 + fn * 16 + l15;
    float w = wjL[jl];
    b2[fn] = w * w;
    ib[fn] = 1.f / fmaxf(w, 1e-7f);
    zj[fn] = zL[j0 + jl];
  }
  float ssum = 0.f;
  float trow[4][4];
  float tcol[4] = {0.f, 0.f, 0.f, 0.f};
#pragma unroll
  for (int fm = 0; fm < 4; ++fm)
#pragma unroll
    for (int rg = 0; rg < 4; ++rg) trow[fm][rg] = 0.f;
#pragma unroll
  for (int fm = 0; fm < 4; ++fm)
#pragma unroll
    for (int fn = 0; fn < 4; ++fn) {
      float ibn = ib[fn];
#pragma unroll
      for (int rg = 0; rg < 4; ++rg) {
        float g = acc[fm][fn][rg];
        float d2 = fmaf(-2.f, g, a2[fm][rg] + b2[fn]);
        float d = sqrtf(fmaxf(d2, 0.f));
        float sim = fmaxf(g, 0.f) * ia[fm][rg] * ibn * exp2f(d * nim);
        if (diag) {
          int il = wi * 64 + fm * 16 + g16 * 4 + rg;
          int jl = wn * 64 + fn * 16 + l15;
          if (il == jl) sim = 0.f;
        }
        ssum += sim;
        trow[fm][rg] = fmaf(sim, zj[fn], trow[fm][rg]);
        tcol[fn] = fmaf(sim, zi[fm][rg], tcol[fn]);
      }
    }
#pragma unroll
  for (int fm = 0; fm < 4; ++fm)
#pragma unroll
    for (int rg = 0; rg < 4; ++rg) {
      float v = trow[fm][rg];
#pragma unroll
      for (int o = 8; o; o >>= 1) v += __shfl_xor(v, o);
      if (l15 == 0) atomicAdd(&tfull[i0 + wi * 64 + fm * 16 + g16 * 4 + rg], v);
    }
  if (!diag) {
#pragma unroll
    for (int fn = 0; fn < 4; ++fn) {
      float v = tcol[fn];
      v += __shfl_xor(v, 16);
      v += __shfl_xor(v, 32);
      if (g16 == 0) atomicAdd(&tfull[j0 + wn * 64 + fn * 16 + l15], v);
    }
  }
  ssum = wave_sum(ssum);
  if (lane == 0) red[wave] = ssum;
  __syncthreads();
  if (t == 0) spart[blk] = ((red[0] + red[1]) + (red[2] + red[3])) * (diag ? 1.f : 2.f);
  tpart[(size_t)blk * NC + t] = tfull[t];
  tpart[(size_t)blk * NC + t + 256] = tfull[t + 256];
}

__global__ __launch_bounds__(256) void mlp_kernel(const float* __restrict__ gap,
                                                  const float* __restrict__ tpart,
                                                  const float* __restrict__ spart,
                                                  const float* __restrict__ wD,
                                                  const float* __restrict__ bD,
                                                  const float* __restrict__ wU,
                                                  const float* __restrict__ bU,
                                                  float* __restrict__ scl) {
  __shared__ float red[4];
  __shared__ float chL[NC];
  __shared__ float hL[NR];
  int b = blockIdx.x, t = threadIdx.x;
  int lane = t & 63, wid = t >> 6;
  float S = 0.f;
#pragma unroll
  for (int k = 0; k < NTASK; ++k) S += spart[b * NTASK + k];
  float invS = 1.f / (S + 1e-10f);
  float t0 = 0.f, t1 = 0.f;
#pragma unroll
  for (int j = 0; j < NTASK; ++j) {
    t0 += tpart[((size_t)b * NTASK + j) * NC + t];
    t1 += tpart[((size_t)b * NTASK + j) * NC + t + 256];
  }
  float g0 = gap[b * NC + t], g1 = gap[b * NC + t + 256];
  float s1 = wave_sum(g0 + g1);
  if (lane == 0) red[wid] = s1;
  __syncthreads();
  float mu = ((red[0] + red[1]) + (red[2] + red[3])) * (1.f / 512.f);
  float e0 = g0 - mu, e1 = g1 - mu;
  __syncthreads();
  float vv = wave_sum(e0 * e0 + e1 * e1);
  if (lane == 0) red[wid] = vv;
  __syncthreads();
  float inv_sd = 1.f / sqrtf(((red[0] + red[1]) + (red[2] + red[3])) * (1.f / 511.f));
  float lm0 = e0 * inv_sd * t0 * invS;
  float lm1 = e1 * inv_sd * t1 * invS;
  __syncthreads();
  float s2 = wave_sum(lm0 + lm1);
  if (lane == 0) red[wid] = s2;
  __syncthreads();
  float m = ((red[0] + red[1]) + (red[2] + red[3])) * (1.f / 512.f);
  float d0 = lm0 - m, d1 = lm1 - m;
  __syncthreads();
  float v2 = wave_sum(d0 * d0 + d1 * d1);
  if (lane == 0) red[wid] = v2;
  __syncthreads();
  float sd = sqrtf(((red[0] + red[1]) + (red[2] + red[3])) * (1.f / 511.f)) + 1e-12f;
  chL[t] = d0 / sd;
  chL[t + 256] = d1 / sd;
  __syncthreads();
  int k = t >> 3, p = t & 7;
  const float* wrow = wD + k * NC + p * 64;
  const float* cp = chL + p * 64;
  float hp = 0.f;
#pragma unroll
  for (int i = 0; i < 64; ++i) hp += wrow[i] * cp[i];
#pragma unroll
  for (int o = 4; o; o >>= 1) hp += __shfl_xor(hp, o);
  if (p == 0) hL[k] = fmaxf(hp + bD[k], 0.f);
  __syncthreads();
#pragma unroll
  for (int u = 0; u < 2; ++u) {
    int c = t + u * 256;
    const float* wrU = wU + c * NR;
    float att = bU[c];
#pragma unroll
    for (int kk = 0; kk < NR; ++kk) att += hL[kk] * wrU[kk];
    scl[b * NC + c] = 1.f / (1.f + __expf(-att));
  }
}

__global__ __launch_bounds__(256) void scale_kernel(const float* __restrict__ x,
                                                    const float* __restrict__ scl,
                                                    float* __restrict__ out) {
  unsigned idx = blockIdx.x * 256u + threadIdx.x;
  unsigned row = idx / 196u;
  float s = scl[row];
  f32x4 v = ((const f32x4*)x)[idx];
  v *= s;
  __builtin_nontemporal_store(v, ((f32x4*)out) + idx);
}

extern "C" void kernel_launch(void* const* d_in, const int* in_sizes, int n_in,
                              void* d_out, int out_size, void* d_ws, size_t ws_size,
                              hipStream_t stream) {
  const float* x = (const float*)d_in[0];
  const float* wD = (const float*)d_in[1];
  const float* bD = (const float*)d_in[2];
  const float* wU = (const float*)d_in[3];
  const float* bU = (const float*)d_in[4];
  float* out = (float*)d_out;
  char* ws = (char*)d_ws;

  __hip_bfloat16* xap = (__hip_bfloat16*)ws;  // 64*512*64*2 = 4 MB
  float* fbase = (float*)(ws + (size_t)NB * NC * KP * 2);
  float* wbuf = fbase;                   // 32768 f32
  float* gap = wbuf + NB * NC;           // 32768
  float* dpart = gap + NB * NC;          // 640
  float* spart = dpart + NB * NTASK;     // 640
  float* tpart = spart + NB * NTASK;     // 64*10*512 = 327680
  float* scl = tpart + NB * NTASK * NC;  // 32768

  void* args[] = {(void*)&x,     (void*)&xap,   (void*)&wbuf, (void*)&gap, (void*)&dpart,
                  (void*)&spart, (void*)&tpart, (void*)&scl,  (void*)&wD,  (void*)&bD,
                  (void*)&wU,    (void*)&bU,    (void*)&out};
  hipError_t err = hipLaunchCooperativeKernel((void*)mega_kernel, dim3(MGRID), dim3(256), args,
                                              0, stream);
  if (err != hipSuccess) {
    (void)hipGetLastError();  // clear error state; use classic path
    hipLaunchKernelGGL(pool_kernel, dim3(NB * NC / 4), dim3(256), 0, stream, x, xap, wbuf, gap);
    hipLaunchKernelGGL(meand_kernel, dim3(NB * NTASK), dim3(256), 0, stream, xap, wbuf, dpart);
    hipLaunchKernelGGL(sim_kernel, dim3(NB * NTASK), dim3(256), 0, stream, xap, wbuf, gap, dpart,
                       tpart, spart);
    hipLaunchKernelGGL(mlp_kernel, dim3(NB), dim3(256), 0, stream, gap, tpart, spart, wD, bD, wU,
                       bU, scl);
    hipLaunchKernelGGL(scale_kernel, dim3(25088), dim3(256), 0, stream, x, scl, out);
  }
}

// Round 5
// 234.076 us; speedup vs baseline: 1.2520x; 1.2520x over previous
//
#include <hip/hip_runtime.h>
#include <hip/hip_bf16.h>
#include <hip/hip_cooperative_groups.h>
#include <stdint.h>

namespace cg = cooperative_groups;

#define NB 64
#define NC 512
#define NHW 784
#define NK 49
#define KP 64
#define NR 32
#define NTASK 10

typedef short sh8 __attribute__((ext_vector_type(8)));
typedef float f32x4 __attribute__((ext_vector_type(4)));
typedef int v4i __attribute__((ext_vector_type(4)));

__device__ __forceinline__ float wave_sum(float v) {
#pragma unroll
  for (int o = 32; o; o >>= 1) v += __shfl_xor(v, o);
  return v;
}

__device__ __forceinline__ void task_decode(int s, int& ti, int& tj) {
  // upper-triangle enumeration: (0,0)(0,1)(0,2)(0,3)(1,1)(1,2)(1,3)(2,2)(2,3)(3,3)
  if (s < 4) { ti = 0; tj = s; }
  else if (s < 7) { ti = 1; tj = s - 3; }
  else if (s < 9) { ti = 2; tj = s - 5; }
  else { ti = 3; tj = 3; }
}

// ---------------- K1: pool 28x28 -> 7x7 bins (bf16, K padded to 64), w=||.||2, gap ----
__global__ __launch_bounds__(256) void pool_kernel(const float* __restrict__ x,
                                                   __hip_bfloat16* __restrict__ xap,
                                                   float* __restrict__ wbuf,
                                                   float* __restrict__ gap) {
  int wid = threadIdx.x >> 6, lane = threadIdx.x & 63;
  int row = blockIdx.x * 4 + wid;  // b*512 + c
  const float* xr = x + (size_t)row * NHW;
  float bin = 0.f;
  if (lane < NK) {
    int pr = lane / 7, pc = lane - pr * 7;
    const float4* p = (const float4*)(xr + pr * 112 + pc * 4);
    float s = 0.f;
#pragma unroll
    for (int i = 0; i < 4; ++i) {
      float4 v = p[i * 7];
      s += (v.x + v.y) + (v.z + v.w);
    }
    bin = s * 0.0625f;
  }
  float s1 = wave_sum(bin);
  float s2 = wave_sum(bin * bin);
  xap[(size_t)row * KP + lane] = __float2bfloat16(bin);  // lanes>=49 write 0 pad
  if (lane == 0) {
    wbuf[row] = sqrtf(s2);         // per-channel L2 norm
    gap[row] = s1 * (1.f / 49.f);  // == mean over 784
  }
}

// =======================================================================
// K2 (cooperative, 640 blocks == #tasks): gram once in registers;
// phase A: dsum -> dpart; grid.sync; phase B: sim epilogue from LIVE acc;
// grid.sync; phase C: MLP on blocks 0..63.
// =======================================================================
__global__ __launch_bounds__(256, 3) void middle_kernel(
    const __hip_bfloat16* __restrict__ xap, const float* __restrict__ wbuf,
    const float* __restrict__ gap, float* __restrict__ dpart, float* __restrict__ spart,
    float* __restrict__ tpart, float* __restrict__ scl, const float* __restrict__ wD,
    const float* __restrict__ bD, const float* __restrict__ wU, const float* __restrict__ bU) {
  cg::grid_group grid = cg::this_grid();
  __shared__ __align__(16) __hip_bfloat16 Ab[128 * KP];
  __shared__ __align__(16) __hip_bfloat16 Bb[128 * KP];
  __shared__ float wiL[128], wjL[128], zL[NC], tfull[NC];
  __shared__ float red[4];
  __shared__ float hL[NR];
  int t = threadIdx.x;
  int lane = t & 63, wave = t >> 6;
  int blk = blockIdx.x;  // == task, 0..639
  int b = blk / NTASK, s = blk - b * NTASK;
  int ti, tj;
  task_decode(s, ti, tj);
  bool diag = (ti == tj);
  int i0 = ti * 128, j0 = tj * 128;

  // ---- stage tiles (XOR-swizzled 16B chunks) + norms + z ----
  const v4i* ga = (const v4i*)(xap + ((size_t)b * NC + i0) * KP);
  const v4i* gb = (const v4i*)(xap + ((size_t)b * NC + j0) * KP);
  v4i* la = (v4i*)Ab;
  v4i* lb = (v4i*)Bb;
#pragma unroll
  for (int q = 0; q < 4; ++q) {
    int cid = q * 256 + t;
    int r = cid >> 3, c = cid & 7;
    int dst = (r << 3) | (c ^ (r & 7));
    la[dst] = ga[cid];
    lb[dst] = gb[cid];
  }
  if (t < 128) {
    wiL[t] = wbuf[b * NC + i0 + t];
    wjL[t] = wbuf[b * NC + j0 + t];
  }
  tfull[t] = 0.f;
  tfull[t + 256] = 0.f;
  // z = (gap - mu)/std (unbiased), bitwise identical wherever recomputed
  float g0 = gap[b * NC + t], g1 = gap[b * NC + t + 256];
  float s1 = wave_sum(g0 + g1);
  if (lane == 0) red[wave] = s1;
  __syncthreads();
  float mu = ((red[0] + red[1]) + (red[2] + red[3])) * (1.f / 512.f);
  float e0 = g0 - mu, e1 = g1 - mu;
  __syncthreads();
  float vv = wave_sum(e0 * e0 + e1 * e1);
  if (lane == 0) red[wave] = vv;
  __syncthreads();
  float inv_sd = 1.f / sqrtf(((red[0] + red[1]) + (red[2] + red[3])) * (1.f / 511.f));
  zL[t] = e0 * inv_sd;
  zL[t + 256] = e1 * inv_sd;
  __syncthreads();

  // ---- fragments + MFMA gram (ONCE; acc stays live across grid.sync) ----
  int wi = wave >> 1, wn = wave & 1;
  int l15 = lane & 15, g16 = lane >> 4;
  sh8 af[4][2], bfr[4][2];
#pragma unroll
  for (int f = 0; f < 4; ++f) {
#pragma unroll
    for (int ks = 0; ks < 2; ++ks) {
      int ra = wi * 64 + f * 16 + l15;
      int rb = wn * 64 + f * 16 + l15;
      int cg2 = ks * 4 + g16;
      af[f][ks] = __builtin_bit_cast(sh8, ((const v4i*)Ab)[(ra << 3) | (cg2 ^ (ra & 7))]);
      bfr[f][ks] = __builtin_bit_cast(sh8, ((const v4i*)Bb)[(rb << 3) | (cg2 ^ (rb & 7))]);
    }
  }
  f32x4 acc[4][4];
#pragma unroll
  for (int fm = 0; fm < 4; ++fm)
#pragma unroll
    for (int fn = 0; fn < 4; ++fn) acc[fm][fn] = (f32x4){0.f, 0.f, 0.f, 0.f};
#pragma unroll
  for (int ks = 0; ks < 2; ++ks)
#pragma unroll
    for (int fm = 0; fm < 4; ++fm)
#pragma unroll
      for (int fn = 0; fn < 4; ++fn)
        acc[fm][fn] =
            __builtin_amdgcn_mfma_f32_16x16x32_bf16(af[fm][ks], bfr[fn][ks], acc[fm][fn], 0, 0, 0);

  float a2[4][4], b2[4];
#pragma unroll
  for (int fm = 0; fm < 4; ++fm)
#pragma unroll
    for (int rg = 0; rg < 4; ++rg) {
      float a = wiL[wi * 64 + fm * 16 + g16 * 4 + rg];
      a2[fm][rg] = a * a;
    }
#pragma unroll
  for (int fn = 0; fn < 4; ++fn) {
    float w = wjL[wn * 64 + fn * 16 + l15];
    b2[fn] = w * w;
  }

  // ---- phase A: dsum ----
  float dsum = 0.f;
#pragma unroll
  for (int fm = 0; fm < 4; ++fm)
#pragma unroll
    for (int fn = 0; fn < 4; ++fn)
#pragma unroll
      for (int rg = 0; rg < 4; ++rg) {
        float d2 = fmaf(-2.f, acc[fm][fn][rg], a2[fm][rg] + b2[fn]);
        dsum += sqrtf(fmaxf(d2, 0.f));
      }
  dsum = wave_sum(dsum);
  if (lane == 0) red[wave] = dsum;
  __syncthreads();
  if (t == 0) dpart[blk] = ((red[0] + red[1]) + (red[2] + red[3])) * (diag ? 1.f : 2.f);
  grid.sync();

  // ---- phase B: sim epilogue (gram still in registers) ----
  float dsb = 0.f;
#pragma unroll
  for (int k = 0; k < NTASK; ++k) dsb += dpart[b * NTASK + k];
  float nim = -1.44269504f / (dsb * (1.f / 262144.f) + 1e-10f);  // -log2e / mean_d
  float ia[4][4], zi[4][4];
#pragma unroll
  for (int fm = 0; fm < 4; ++fm)
#pragma unroll
    for (int rg = 0; rg < 4; ++rg) {
      int il = wi * 64 + fm * 16 + g16 * 4 + rg;
      ia[fm][rg] = 1.f / fmaxf(wiL[il], 1e-7f);
      zi[fm][rg] = zL[i0 + il];
    }
  float ib[4], zj[4];
#pragma unroll
  for (int fn = 0; fn < 4; ++fn) {
    int jl = wn * 64 + fn * 16 + l15;
    ib[fn] = 1.f / fmaxf(wjL[jl], 1e-7f);
    zj[fn] = zL[j0 + jl];
  }
  float ssum = 0.f;
  float trow[4][4];
  float tcol[4] = {0.f, 0.f, 0.f, 0.f};
#pragma unroll
  for (int fm = 0; fm < 4; ++fm)
#pragma unroll
    for (int rg = 0; rg < 4; ++rg) trow[fm][rg] = 0.f;
#pragma unroll
  for (int fm = 0; fm < 4; ++fm)
#pragma unroll
    for (int fn = 0; fn < 4; ++fn) {
      float ibn = ib[fn];
#pragma unroll
      for (int rg = 0; rg < 4; ++rg) {
        float g = acc[fm][fn][rg];
        float d2 = fmaf(-2.f, g, a2[fm][rg] + b2[fn]);
        float d = sqrtf(fmaxf(d2, 0.f));
        float sim = fmaxf(g, 0.f) * ia[fm][rg] * ibn * exp2f(d * nim);
        if (diag) {
          int il = wi * 64 + fm * 16 + g16 * 4 + rg;
          int jl = wn * 64 + fn * 16 + l15;
          if (il == jl) sim = 0.f;
        }
        ssum += sim;
        trow[fm][rg] = fmaf(sim, zj[fn], trow[fm][rg]);
        tcol[fn] = fmaf(sim, zi[fm][rg], tcol[fn]);
      }
    }
#pragma unroll
  for (int fm = 0; fm < 4; ++fm)
#pragma unroll
    for (int rg = 0; rg < 4; ++rg) {
      float v = trow[fm][rg];
#pragma unroll
      for (int o = 8; o; o >>= 1) v += __shfl_xor(v, o);
      if (l15 == 0) atomicAdd(&tfull[i0 + wi * 64 + fm * 16 + g16 * 4 + rg], v);
    }
  if (!diag) {
#pragma unroll
    for (int fn = 0; fn < 4; ++fn) {
      float v = tcol[fn];
      v += __shfl_xor(v, 16);
      v += __shfl_xor(v, 32);
      if (g16 == 0) atomicAdd(&tfull[j0 + wn * 64 + fn * 16 + l15], v);
    }
  }
  ssum = wave_sum(ssum);
  if (lane == 0) red[wave] = ssum;
  __syncthreads();
  if (t == 0) spart[blk] = ((red[0] + red[1]) + (red[2] + red[3])) * (diag ? 1.f : 2.f);
  tpart[(size_t)blk * NC + t] = tfull[t];
  tpart[(size_t)blk * NC + t + 256] = tfull[t + 256];
  grid.sync();

  // ---- phase C: MLP, blocks 0..63 (batch = blk) ----
  if (blk < NB) {
    int bb = blk;
    float* chL = tfull;  // reuse (safe: grid.sync above)
    float S = 0.f;
#pragma unroll
    for (int k = 0; k < NTASK; ++k) S += spart[bb * NTASK + k];
    float invS = 1.f / (S + 1e-10f);
    float t0 = 0.f, t1 = 0.f;
#pragma unroll
    for (int j = 0; j < NTASK; ++j) {
      t0 += tpart[((size_t)bb * NTASK + j) * NC + t];
      t1 += tpart[((size_t)bb * NTASK + j) * NC + t + 256];
    }
    float h0 = gap[bb * NC + t], h1 = gap[bb * NC + t + 256];
    float q1 = wave_sum(h0 + h1);
    if (lane == 0) red[wave] = q1;
    __syncthreads();
    float mu2 = ((red[0] + red[1]) + (red[2] + red[3])) * (1.f / 512.f);
    float f0 = h0 - mu2, f1 = h1 - mu2;
    __syncthreads();
    float q2 = wave_sum(f0 * f0 + f1 * f1);
    if (lane == 0) red[wave] = q2;
    __syncthreads();
    float isd = 1.f / sqrtf(((red[0] + red[1]) + (red[2] + red[3])) * (1.f / 511.f));
    float lm0 = f0 * isd * t0 * invS;
    float lm1 = f1 * isd * t1 * invS;
    __syncthreads();
    float q3 = wave_sum(lm0 + lm1);
    if (lane == 0) red[wave] = q3;
    __syncthreads();
    float m = ((red[0] + red[1]) + (red[2] + red[3])) * (1.f / 512.f);
    float d0 = lm0 - m, d1 = lm1 - m;
    __syncthreads();
    float q4 = wave_sum(d0 * d0 + d1 * d1);
    if (lane == 0) red[wave] = q4;
    __syncthreads();
    float sd = sqrtf(((red[0] + red[1]) + (red[2] + red[3])) * (1.f / 511.f)) + 1e-12f;
    chL[t] = d0 / sd;
    chL[t + 256] = d1 / sd;
    __syncthreads();
    int k = t >> 3, p = t & 7;
    const float* wrow = wD + k * NC + p * 64;
    const float* cp = chL + p * 64;
    float hp = 0.f;
#pragma unroll
    for (int i = 0; i < 64; ++i) hp += wrow[i] * cp[i];
#pragma unroll
    for (int o = 4; o; o >>= 1) hp += __shfl_xor(hp, o);
    if (p == 0) hL[k] = fmaxf(hp + bD[k], 0.f);
    __syncthreads();
#pragma unroll
    for (int u = 0; u < 2; ++u) {
      int c = t + u * 256;
      const float* wrU = wU + c * NR;
      float att = bU[c];
#pragma unroll
      for (int kk = 0; kk < NR; ++kk) att += hL[kk] * wrU[kk];
      scl[bb * NC + c] = 1.f / (1.f + __expf(-att));
    }
  }
}

// ---------------- K3: out = x * scale (x from L3; NT store for out) ----------------
__global__ __launch_bounds__(256) void scale_kernel(const float* __restrict__ x,
                                                    const float* __restrict__ scl,
                                                    float* __restrict__ out) {
  unsigned idx = blockIdx.x * 256u + threadIdx.x;  // float4 index, total 6422528
  unsigned row = idx / 196u;                       // b*512 + c
  float s = scl[row];
  f32x4 v = ((const f32x4*)x)[idx];
  v *= s;
  __builtin_nontemporal_store(v, ((f32x4*)out) + idx);
}

// =======================================================================
// Fallback classic middle kernels (round-3, proven) — if coop launch fails
// =======================================================================
__global__ __launch_bounds__(256) void meand_kernel(const __hip_bfloat16* __restrict__ xap,
                                                    const float* __restrict__ wbuf,
                                                    float* __restrict__ dpart) {
  __shared__ __align__(16) __hip_bfloat16 Ab[128 * KP];
  __shared__ __align__(16) __hip_bfloat16 Bb[128 * KP];
  __shared__ float wiL[128], wjL[128];
  __shared__ float red[4];
  int blk = blockIdx.x;
  int b = blk / NTASK, s = blk - b * NTASK;
  int ti, tj;
  task_decode(s, ti, tj);
  bool diag = (ti == tj);
  int i0 = ti * 128, j0 = tj * 128;
  int t = threadIdx.x;
  const v4i* ga = (const v4i*)(xap + ((size_t)b * NC + i0) * KP);
  const v4i* gb = (const v4i*)(xap + ((size_t)b * NC + j0) * KP);
  v4i* la = (v4i*)Ab;
  v4i* lb = (v4i*)Bb;
#pragma unroll
  for (int q = 0; q < 4; ++q) {
    int cid = q * 256 + t;
    int r = cid >> 3, c = cid & 7;
    int dst = (r << 3) | (c ^ (r & 7));
    la[dst] = ga[cid];
    lb[dst] = gb[cid];
  }
  if (t < 128) {
    wiL[t] = wbuf[b * NC + i0 + t];
    wjL[t] = wbuf[b * NC + j0 + t];
  }
  __syncthreads();
  int lane = t & 63, wave = t >> 6;
  int wi = wave >> 1, wn = wave & 1;
  int l15 = lane & 15, g16 = lane >> 4;
  sh8 af[4][2], bfr[4][2];
#pragma unroll
  for (int f = 0; f < 4; ++f) {
#pragma unroll
    for (int ks = 0; ks < 2; ++ks) {
      int ra = wi * 64 + f * 16 + l15;
      int rb = wn * 64 + f * 16 + l15;
      int cg2 = ks * 4 + g16;
      af[f][ks] = __builtin_bit_cast(sh8, ((const v4i*)Ab)[(ra << 3) | (cg2 ^ (ra & 7))]);
      bfr[f][ks] = __builtin_bit_cast(sh8, ((const v4i*)Bb)[(rb << 3) | (cg2 ^ (rb & 7))]);
    }
  }
  f32x4 acc[4][4];
#pragma unroll
  for (int fm = 0; fm < 4; ++fm)
#pragma unroll
    for (int fn = 0; fn < 4; ++fn) acc[fm][fn] = (f32x4){0.f, 0.f, 0.f, 0.f};
#pragma unroll
  for (int ks = 0; ks < 2; ++ks)
#pragma unroll
    for (int fm = 0; fm < 4; ++fm)
#pragma unroll
      for (int fn = 0; fn < 4; ++fn)
        acc[fm][fn] =
            __builtin_amdgcn_mfma_f32_16x16x32_bf16(af[fm][ks], bfr[fn][ks], acc[fm][fn], 0, 0, 0);
  float a2[4][4], b2[4];
#pragma unroll
  for (int fm = 0; fm < 4; ++fm)
#pragma unroll
    for (int rg = 0; rg < 4; ++rg) {
      float a = wiL[wi * 64 + fm * 16 + g16 * 4 + rg];
      a2[fm][rg] = a * a;
    }
#pragma unroll
  for (int fn = 0; fn < 4; ++fn) {
    float w = wjL[wn * 64 + fn * 16 + l15];
    b2[fn] = w * w;
  }
  float dsum = 0.f;
#pragma unroll
  for (int fm = 0; fm < 4; ++fm)
#pragma unroll
    for (int fn = 0; fn < 4; ++fn)
#pragma unroll
      for (int rg = 0; rg < 4; ++rg) {
        float d2 = fmaf(-2.f, acc[fm][fn][rg], a2[fm][rg] + b2[fn]);
        dsum += sqrtf(fmaxf(d2, 0.f));
      }
  dsum = wave_sum(dsum);
  if (lane == 0) red[wave] = dsum;
  __syncthreads();
  if (t == 0) dpart[blk] = ((red[0] + red[1]) + (red[2] + red[3])) * (diag ? 1.f : 2.f);
}

__global__ __launch_bounds__(256) void sim_kernel(const __hip_bfloat16* __restrict__ xap,
                                                  const float* __restrict__ wbuf,
                                                  const float* __restrict__ gap,
                                                  const float* __restrict__ dpart,
                                                  float* __restrict__ tpart,
                                                  float* __restrict__ spart) {
  __shared__ __align__(16) __hip_bfloat16 Ab[128 * KP];
  __shared__ __align__(16) __hip_bfloat16 Bb[128 * KP];
  __shared__ float wiL[128], wjL[128], zL[NC], tfull[NC];
  __shared__ float red[4];
  int blk = blockIdx.x;
  int b = blk / NTASK, s = blk - b * NTASK;
  int ti, tj;
  task_decode(s, ti, tj);
  bool diag = (ti == tj);
  int i0 = ti * 128, j0 = tj * 128;
  int t = threadIdx.x;
  int lane = t & 63, wave = t >> 6;
  float dsb = 0.f;
#pragma unroll
  for (int k = 0; k < NTASK; ++k) dsb += dpart[b * NTASK + k];
  float nim = -1.44269504f / (dsb * (1.f / 262144.f) + 1e-10f);
  const v4i* ga = (const v4i*)(xap + ((size_t)b * NC + i0) * KP);
  const v4i* gb = (const v4i*)(xap + ((size_t)b * NC + j0) * KP);
  v4i* la = (v4i*)Ab;
  v4i* lb = (v4i*)Bb;
#pragma unroll
  for (int q = 0; q < 4; ++q) {
    int cid = q * 256 + t;
    int r = cid >> 3, c = cid & 7;
    int dst = (r << 3) | (c ^ (r & 7));
    la[dst] = ga[cid];
    lb[dst] = gb[cid];
  }
  if (t < 128) {
    wiL[t] = wbuf[b * NC + i0 + t];
    wjL[t] = wbuf[b * NC + j0 + t];
  }
  tfull[t] = 0.f;
  tfull[t + 256] = 0.f;
  float g0 = gap[b * NC + t], g1 = gap[b * NC + t + 256];
  float s1 = wave_sum(g0 + g1);
  if (lane == 0) red[wave] = s1;
  __syncthreads();
  float mu = ((red[0] + red[1]) + (red[2] + red[3])) * (1.f / 512.f);
  float e0 = g0 - mu, e1 = g1 - mu;
  __syncthreads();
  float vv = wave_sum(e0 * e0 + e1 * e1);
  if (lane == 0) red[wave] = vv;
  __syncthreads();
  float inv_sd = 1.f / sqrtf(((red[0] + red[1]) + (red[2] + red[3])) * (1.f / 511.f));
  zL[t] = e0 * inv_sd;
  zL[t + 256] = e1 * inv_sd;
  __syncthreads();
  int wi = wave >> 1, wn = wave & 1;
  int l15 = lane & 15, g16 = lane >> 4;
  sh8 af[4][2], bfr[4][2];
#pragma unroll
  for (int f = 0; f < 4; ++f) {
#pragma unroll
    for (int ks = 0; ks < 2; ++ks) {
      int ra = wi * 64 + f * 16 + l15;
      int rb = wn * 64 + f * 16 + l15;
      int cg2 = ks * 4 + g16;
      af[f][ks] = __builtin_bit_cast(sh8, ((const v4i*)Ab)[(ra << 3) | (cg2 ^ (ra & 7))]);
      bfr[f][ks] = __builtin_bit_cast(sh8, ((const v4i*)Bb)[(rb << 3) | (cg2 ^ (rb & 7))]);
    }
  }
  f32x4 acc[4][4];
#pragma unroll
  for (int fm = 0; fm < 4; ++fm)
#pragma unroll
    for (int fn = 0; fn < 4; ++fn) acc[fm][fn] = (f32x4){0.f, 0.f, 0.f, 0.f};
#pragma unroll
  for (int ks = 0; ks < 2; ++ks)
#pragma unroll
    for (int fm = 0; fm < 4; ++fm)
#pragma unroll
      for (int fn = 0; fn < 4; ++fn)
        acc[fm][fn] =
            __builtin_amdgcn_mfma_f32_16x16x32_bf16(af[fm][ks], bfr[fn][ks], acc[fm][fn], 0, 0, 0);
  float a2[4][4], ia[4][4], zi[4][4];
#pragma unroll
  for (int fm = 0; fm < 4; ++fm)
#pragma unroll
    for (int rg = 0; rg < 4; ++rg) {
      int il = wi * 64 + fm * 16 + g16 * 4 + rg;
      float a = wiL[il];
      a2[fm][rg] = a * a;
      ia[fm][rg] = 1.f / fmaxf(a, 1e-7f);
      zi[fm][rg] = zL[i0 + il];
    }
  float b2[4], ib[4], zj[4];
#pragma unroll
  for (int fn = 0; fn < 4; ++fn) {
    int jl = wn * 64 + fn * 16 + l15;
    float w = wjL[jl];
    b2[fn] = w * w;
    ib[fn] = 1.f / fmaxf(w, 1e-7f);
    zj[fn] = zL[j0 + jl];
  }
  float ssum = 0.f;
  float trow[4][4];
  float tcol[4] = {0.f, 0.f, 0.f, 0.f};
#pragma unroll
  for (int fm = 0; fm < 4; ++fm)
#pragma unroll
    for (int rg = 0; rg < 4; ++rg) trow[fm][rg] = 0.f;
#pragma unroll
  for (int fm = 0; fm < 4; ++fm)
#pragma unroll
    for (int fn = 0; fn < 4; ++fn) {
      float ibn = ib[fn];
#pragma unroll
      for (int rg = 0; rg < 4; ++rg) {
        float g = acc[fm][fn][rg];
        float d2 = fmaf(-2.f, g, a2[fm][rg] + b2[fn]);
        float d = sqrtf(fmaxf(d2, 0.f));
        float sim = fmaxf(g, 0.f) * ia[fm][rg] * ibn * exp2f(d * nim);
        if (diag) {
          int il = wi * 64 + fm * 16 + g16 * 4 + rg;
          int jl = wn * 64 + fn * 16 + l15;
          if (il == jl) sim = 0.f;
        }
        ssum += sim;
        trow[fm][rg] = fmaf(sim, zj[fn], trow[fm][rg]);
        tcol[fn] = fmaf(sim, zi[fm][rg], tcol[fn]);
      }
    }
#pragma unroll
  for (int fm = 0; fm < 4; ++fm)
#pragma unroll
    for (int rg = 0; rg < 4; ++rg) {
      float v = trow[fm][rg];
#pragma unroll
      for (int o = 8; o; o >>= 1) v += __shfl_xor(v, o);
      if (l15 == 0) atomicAdd(&tfull[i0 + wi * 64 + fm * 16 + g16 * 4 + rg], v);
    }
  if (!diag) {
#pragma unroll
    for (int fn = 0; fn < 4; ++fn) {
      float v = tcol[fn];
      v += __shfl_xor(v, 16);
      v += __shfl_xor(v, 32);
      if (g16 == 0) atomicAdd(&tfull[j0 + wn * 64 + fn * 16 + l15], v);
    }
  }
  ssum = wave_sum(ssum);
  if (lane == 0) red[wave] = ssum;
  __syncthreads();
  if (t == 0) spart[blk] = ((red[0] + red[1]) + (red[2] + red[3])) * (diag ? 1.f : 2.f);
  tpart[(size_t)blk * NC + t] = tfull[t];
  tpart[(size_t)blk * NC + t + 256] = tfull[t + 256];
}

__global__ __launch_bounds__(256) void mlp_kernel(const float* __restrict__ gap,
                                                  const float* __restrict__ tpart,
                                                  const float* __restrict__ spart,
                                                  const float* __restrict__ wD,
                                                  const float* __restrict__ bD,
                                                  const float* __restrict__ wU,
                                                  const float* __restrict__ bU,
                                                  float* __restrict__ scl) {
  __shared__ float red[4];
  __shared__ float chL[NC];
  __shared__ float hL[NR];
  int b = blockIdx.x, t = threadIdx.x;
  int lane = t & 63, wid = t >> 6;
  float S = 0.f;
#pragma unroll
  for (int k = 0; k < NTASK; ++k) S += spart[b * NTASK + k];
  float invS = 1.f / (S + 1e-10f);
  float t0 = 0.f, t1 = 0.f;
#pragma unroll
  for (int j = 0; j < NTASK; ++j) {
    t0 += tpart[((size_t)b * NTASK + j) * NC + t];
    t1 += tpart[((size_t)b * NTASK + j) * NC + t + 256];
  }
  float g0 = gap[b * NC + t], g1 = gap[b * NC + t + 256];
  float s1 = wave_sum(g0 + g1);
  if (lane == 0) red[wid] = s1;
  __syncthreads();
  float mu = ((red[0] + red[1]) + (red[2] + red[3])) * (1.f / 512.f);
  float e0 = g0 - mu, e1 = g1 - mu;
  __syncthreads();
  float vv = wave_sum(e0 * e0 + e1 * e1);
  if (lane == 0) red[wid] = vv;
  __syncthreads();
  float inv_sd = 1.f / sqrtf(((red[0] + red[1]) + (red[2] + red[3])) * (1.f / 511.f));
  float lm0 = e0 * inv_sd * t0 * invS;
  float lm1 = e1 * inv_sd * t1 * invS;
  __syncthreads();
  float s2 = wave_sum(lm0 + lm1);
  if (lane == 0) red[wid] = s2;
  __syncthreads();
  float m = ((red[0] + red[1]) + (red[2] + red[3])) * (1.f / 512.f);
  float d0 = lm0 - m, d1 = lm1 - m;
  __syncthreads();
  float v2 = wave_sum(d0 * d0 + d1 * d1);
  if (lane == 0) red[wid] = v2;
  __syncthreads();
  float sd = sqrtf(((red[0] + red[1]) + (red[2] + red[3])) * (1.f / 511.f)) + 1e-12f;
  chL[t] = d0 / sd;
  chL[t + 256] = d1 / sd;
  __syncthreads();
  int k = t >> 3, p = t & 7;
  const float* wrow = wD + k * NC + p * 64;
  const float* cp = chL + p * 64;
  float hp = 0.f;
#pragma unroll
  for (int i = 0; i < 64; ++i) hp += wrow[i] * cp[i];
#pragma unroll
  for (int o = 4; o; o >>= 1) hp += __shfl_xor(hp, o);
  if (p == 0) hL[k] = fmaxf(hp + bD[k], 0.f);
  __syncthreads();
#pragma unroll
  for (int u = 0; u < 2; ++u) {
    int c = t + u * 256;
    const float* wrU = wU + c * NR;
    float att = bU[c];
#pragma unroll
    for (int kk = 0; kk < NR; ++kk) att += hL[kk] * wrU[kk];
    scl[b * NC + c] = 1.f / (1.f + __expf(-att));
  }
}

extern "C" void kernel_launch(void* const* d_in, const int* in_sizes, int n_in,
                              void* d_out, int out_size, void* d_ws, size_t ws_size,
                              hipStream_t stream) {
  const float* x = (const float*)d_in[0];
  const float* wD = (const float*)d_in[1];
  const float* bD = (const float*)d_in[2];
  const float* wU = (const float*)d_in[3];
  const float* bU = (const float*)d_in[4];
  float* out = (float*)d_out;
  char* ws = (char*)d_ws;

  __hip_bfloat16* xap = (__hip_bfloat16*)ws;  // 64*512*64*2 = 4 MB
  float* fbase = (float*)(ws + (size_t)NB * NC * KP * 2);
  float* wbuf = fbase;                   // 32768 f32
  float* gap = wbuf + NB * NC;           // 32768
  float* dpart = gap + NB * NC;          // 640
  float* spart = dpart + NB * NTASK;     // 640
  float* tpart = spart + NB * NTASK;     // 64*10*512 = 327680
  float* scl = tpart + NB * NTASK * NC;  // 32768

  hipLaunchKernelGGL(pool_kernel, dim3(NB * NC / 4), dim3(256), 0, stream, x, xap, wbuf, gap);

  void* args[] = {(void*)&xap,   (void*)&wbuf, (void*)&gap, (void*)&dpart, (void*)&spart,
                  (void*)&tpart, (void*)&scl,  (void*)&wD,  (void*)&bD,    (void*)&wU,
                  (void*)&bU};
  hipError_t err = hipLaunchCooperativeKernel((void*)middle_kernel, dim3(NB * NTASK), dim3(256),
                                              args, 0, stream);
  if (err != hipSuccess) {
    (void)hipGetLastError();  // clear; classic fallback
    hipLaunchKernelGGL(meand_kernel, dim3(NB * NTASK), dim3(256), 0, stream, xap, wbuf, dpart);
    hipLaunchKernelGGL(sim_kernel, dim3(NB * NTASK), dim3(256), 0, stream, xap, wbuf, gap, dpart,
                       tpart, spart);
    hipLaunchKernelGGL(mlp_kernel, dim3(NB), dim3(256), 0, stream, gap, tpart, spart, wD, bD, wU,
                       bU, scl);
  }

  hipLaunchKernelGGL(scale_kernel, dim3(25088), dim3(256), 0, stream, x, scl, out);
}

// Round 6
// 192.067 us; speedup vs baseline: 1.5259x; 1.2187x over previous
//
#include <hip/hip_runtime.h>
#include <hip/hip_bf16.h>
#include <stdint.h>

#define NB 64
#define NC 512
#define NHW 784
#define NK 49
#define KP 64
#define NR 32
#define NTASK 10

typedef short sh8 __attribute__((ext_vector_type(8)));
typedef float f32x4 __attribute__((ext_vector_type(4)));
typedef int v4i __attribute__((ext_vector_type(4)));

__device__ __forceinline__ float wave_sum(float v) {
#pragma unroll
  for (int o = 32; o; o >>= 1) v += __shfl_xor(v, o);
  return v;
}

__device__ __forceinline__ void task_decode(int s, int& ti, int& tj) {
  // upper-triangle enumeration: (0,0)(0,1)(0,2)(0,3)(1,1)(1,2)(1,3)(2,2)(2,3)(3,3)
  if (s < 4) { ti = 0; tj = s; }
  else if (s < 7) { ti = 1; tj = s - 3; }
  else if (s < 9) { ti = 2; tj = s - 5; }
  else { ti = 3; tj = 3; }
}

// ---------------- K1: pool, fully-coalesced loads + LDS bin accumulation ----------------
// wave = one row (784 floats = 196 float4). float4 f -> bin (f/28)*7 + f%7.
__global__ __launch_bounds__(256) void pool_kernel(const float* __restrict__ x,
                                                   __hip_bfloat16* __restrict__ xap,
                                                   float* __restrict__ wbuf,
                                                   float* __restrict__ gap,
                                                   int* __restrict__ cnt) {
  __shared__ float bins[4][64];
  int t = threadIdx.x, wid = t >> 6, lane = t & 63;
  if (blockIdx.x == 0 && t < NB) cnt[t] = 0;  // zero batch counters (used by sim later)
  int row = blockIdx.x * 4 + wid;  // b*512 + c
  const f32x4* xr = (const f32x4*)(x + (size_t)row * NHW);
  bins[wid][lane] = 0.f;
  __syncthreads();
#pragma unroll
  for (int i = 0; i < 3; ++i) {
    int f = i * 64 + lane;
    f32x4 v = xr[f];
    float s = (v.x + v.y) + (v.z + v.w);
    int bi = (f / 28) * 7 + f % 7;
    atomicAdd(&bins[wid][bi], s);
  }
  if (lane < 4) {
    int f = 192 + lane;
    f32x4 v = xr[f];
    float s = (v.x + v.y) + (v.z + v.w);
    int bi = (f / 28) * 7 + f % 7;
    atomicAdd(&bins[wid][bi], s);
  }
  __syncthreads();
  float bin = bins[wid][lane] * 0.0625f;  // lanes>=49 stay 0 (pad)
  float s1 = wave_sum(bin);
  float s2 = wave_sum(bin * bin);
  xap[(size_t)row * KP + lane] = __float2bfloat16(bin);
  if (lane == 0) {
    wbuf[row] = sqrtf(s2);         // per-channel L2 norm
    gap[row] = s1 * (1.f / 49.f);  // == mean over 784
  }
}

// ---------------- K2: pass A — weighted sum of d per (batch, triangle-tile) ----------------
__global__ __launch_bounds__(256) void meand_kernel(const __hip_bfloat16* __restrict__ xap,
                                                    const float* __restrict__ wbuf,
                                                    float* __restrict__ dpart) {
  __shared__ __align__(16) __hip_bfloat16 Ab[128 * KP];
  __shared__ __align__(16) __hip_bfloat16 Bb[128 * KP];
  __shared__ float wiL[128], wjL[128];
  __shared__ float red[4];
  int blk = blockIdx.x;
  int b = blk / NTASK, s = blk - b * NTASK;
  int ti, tj;
  task_decode(s, ti, tj);
  bool diag = (ti == tj);
  int i0 = ti * 128, j0 = tj * 128;
  int t = threadIdx.x;
  const v4i* ga = (const v4i*)(xap + ((size_t)b * NC + i0) * KP);
  const v4i* gb = (const v4i*)(xap + ((size_t)b * NC + j0) * KP);
  v4i* la = (v4i*)Ab;
  v4i* lb = (v4i*)Bb;
#pragma unroll
  for (int q = 0; q < 4; ++q) {
    int cid = q * 256 + t;
    int r = cid >> 3, c = cid & 7;
    int dst = (r << 3) | (c ^ (r & 7));
    la[dst] = ga[cid];
    lb[dst] = gb[cid];
  }
  if (t < 128) {
    wiL[t] = wbuf[b * NC + i0 + t];
    wjL[t] = wbuf[b * NC + j0 + t];
  }
  __syncthreads();
  int lane = t & 63, wave = t >> 6;
  int wi = wave >> 1, wn = wave & 1;
  int l15 = lane & 15, g16 = lane >> 4;
  sh8 af[4][2], bfr[4][2];
#pragma unroll
  for (int f = 0; f < 4; ++f) {
#pragma unroll
    for (int ks = 0; ks < 2; ++ks) {
      int ra = wi * 64 + f * 16 + l15;
      int rb = wn * 64 + f * 16 + l15;
      int cg2 = ks * 4 + g16;
      af[f][ks] = __builtin_bit_cast(sh8, ((const v4i*)Ab)[(ra << 3) | (cg2 ^ (ra & 7))]);
      bfr[f][ks] = __builtin_bit_cast(sh8, ((const v4i*)Bb)[(rb << 3) | (cg2 ^ (rb & 7))]);
    }
  }
  f32x4 acc[4][4];
#pragma unroll
  for (int fm = 0; fm < 4; ++fm)
#pragma unroll
    for (int fn = 0; fn < 4; ++fn) acc[fm][fn] = (f32x4){0.f, 0.f, 0.f, 0.f};
#pragma unroll
  for (int ks = 0; ks < 2; ++ks)
#pragma unroll
    for (int fm = 0; fm < 4; ++fm)
#pragma unroll
      for (int fn = 0; fn < 4; ++fn)
        acc[fm][fn] =
            __builtin_amdgcn_mfma_f32_16x16x32_bf16(af[fm][ks], bfr[fn][ks], acc[fm][fn], 0, 0, 0);
  float a2[4][4], b2[4];
#pragma unroll
  for (int fm = 0; fm < 4; ++fm)
#pragma unroll
    for (int rg = 0; rg < 4; ++rg) {
      float a = wiL[wi * 64 + fm * 16 + g16 * 4 + rg];
      a2[fm][rg] = a * a;
    }
#pragma unroll
  for (int fn = 0; fn < 4; ++fn) {
    float w = wjL[wn * 64 + fn * 16 + l15];
    b2[fn] = w * w;
  }
  float dsum = 0.f;
#pragma unroll
  for (int fm = 0; fm < 4; ++fm)
#pragma unroll
    for (int fn = 0; fn < 4; ++fn)
#pragma unroll
      for (int rg = 0; rg < 4; ++rg) {
        float d2 = fmaf(-2.f, acc[fm][fn][rg], a2[fm][rg] + b2[fn]);
        dsum += sqrtf(fmaxf(d2, 0.f));
      }
  dsum = wave_sum(dsum);
  if (lane == 0) red[wave] = dsum;
  __syncthreads();
  if (t == 0) dpart[blk] = ((red[0] + red[1]) + (red[2] + red[3])) * (diag ? 1.f : 2.f);
}

// ---------------- K3: pass B — sim epilogue; last block per batch also runs the MLP ----
__global__ __launch_bounds__(256) void sim_kernel(const __hip_bfloat16* __restrict__ xap,
                                                  const float* __restrict__ wbuf,
                                                  const float* __restrict__ gap,
                                                  const float* __restrict__ dpart,
                                                  float* __restrict__ tpart,
                                                  float* __restrict__ spart,
                                                  const float* __restrict__ wD,
                                                  const float* __restrict__ bD,
                                                  const float* __restrict__ wU,
                                                  const float* __restrict__ bU,
                                                  float* __restrict__ scl,
                                                  int* __restrict__ cnt) {
  __shared__ __align__(16) __hip_bfloat16 Ab[128 * KP];
  __shared__ __align__(16) __hip_bfloat16 Bb[128 * KP];
  __shared__ float wiL[128], wjL[128], zL[NC], tfull[NC];
  __shared__ float red[4];
  __shared__ float hL[NR];
  __shared__ int lastFlag;
  int blk = blockIdx.x;
  int b = blk / NTASK, s = blk - b * NTASK;
  int ti, tj;
  task_decode(s, ti, tj);
  bool diag = (ti == tj);
  int i0 = ti * 128, j0 = tj * 128;
  int t = threadIdx.x;
  int lane = t & 63, wave = t >> 6;
  float dsb = 0.f;
#pragma unroll
  for (int k = 0; k < NTASK; ++k) dsb += dpart[b * NTASK + k];
  float nim = -1.44269504f / (dsb * (1.f / 262144.f) + 1e-10f);  // -log2e / mean_d
  const v4i* ga = (const v4i*)(xap + ((size_t)b * NC + i0) * KP);
  const v4i* gb = (const v4i*)(xap + ((size_t)b * NC + j0) * KP);
  v4i* la = (v4i*)Ab;
  v4i* lb = (v4i*)Bb;
#pragma unroll
  for (int q = 0; q < 4; ++q) {
    int cid = q * 256 + t;
    int r = cid >> 3, c = cid & 7;
    int dst = (r << 3) | (c ^ (r & 7));
    la[dst] = ga[cid];
    lb[dst] = gb[cid];
  }
  if (t < 128) {
    wiL[t] = wbuf[b * NC + i0 + t];
    wjL[t] = wbuf[b * NC + j0 + t];
  }
  tfull[t] = 0.f;
  tfull[t + 256] = 0.f;
  // z = (gap - mu)/std (unbiased), bitwise identical wherever recomputed
  float g0 = gap[b * NC + t], g1 = gap[b * NC + t + 256];
  float s1 = wave_sum(g0 + g1);
  if (lane == 0) red[wave] = s1;
  __syncthreads();
  float mu = ((red[0] + red[1]) + (red[2] + red[3])) * (1.f / 512.f);
  float e0 = g0 - mu, e1 = g1 - mu;
  __syncthreads();
  float vv = wave_sum(e0 * e0 + e1 * e1);
  if (lane == 0) red[wave] = vv;
  __syncthreads();
  float inv_sd = 1.f / sqrtf(((red[0] + red[1]) + (red[2] + red[3])) * (1.f / 511.f));
  zL[t] = e0 * inv_sd;
  zL[t + 256] = e1 * inv_sd;
  __syncthreads();
  int wi = wave >> 1, wn = wave & 1;
  int l15 = lane & 15, g16 = lane >> 4;
  sh8 af[4][2], bfr[4][2];
#pragma unroll
  for (int f = 0; f < 4; ++f) {
#pragma unroll
    for (int ks = 0; ks < 2; ++ks) {
      int ra = wi * 64 + f * 16 + l15;
      int rb = wn * 64 + f * 16 + l15;
      int cg2 = ks * 4 + g16;
      af[f][ks] = __builtin_bit_cast(sh8, ((const v4i*)Ab)[(ra << 3) | (cg2 ^ (ra & 7))]);
      bfr[f][ks] = __builtin_bit_cast(sh8, ((const v4i*)Bb)[(rb << 3) | (cg2 ^ (rb & 7))]);
    }
  }
  f32x4 acc[4][4];
#pragma unroll
  for (int fm = 0; fm < 4; ++fm)
#pragma unroll
    for (int fn = 0; fn < 4; ++fn) acc[fm][fn] = (f32x4){0.f, 0.f, 0.f, 0.f};
#pragma unroll
  for (int ks = 0; ks < 2; ++ks)
#pragma unroll
    for (int fm = 0; fm < 4; ++fm)
#pragma unroll
      for (int fn = 0; fn < 4; ++fn)
        acc[fm][fn] =
            __builtin_amdgcn_mfma_f32_16x16x32_bf16(af[fm][ks], bfr[fn][ks], acc[fm][fn], 0, 0, 0);
  float a2[4][4], ia[4][4], zi[4][4];
#pragma unroll
  for (int fm = 0; fm < 4; ++fm)
#pragma unroll
    for (int rg = 0; rg < 4; ++rg) {
      int il = wi * 64 + fm * 16 + g16 * 4 + rg;
      float a = wiL[il];
      a2[fm][rg] = a * a;
      ia[fm][rg] = 1.f / fmaxf(a, 1e-7f);
      zi[fm][rg] = zL[i0 + il];
    }
  float b2[4], ib[4], zj[4];
#pragma unroll
  for (int fn = 0; fn < 4; ++fn) {
    int jl = wn * 64 + fn * 16 + l15;
    float w = wjL[jl];
    b2[fn] = w * w;
    ib[fn] = 1.f / fmaxf(w, 1e-7f);
    zj[fn] = zL[j0 + jl];
  }
  float ssum = 0.f;
  float trow[4][4];
  float tcol[4] = {0.f, 0.f, 0.f, 0.f};
#pragma unroll
  for (int fm = 0; fm < 4; ++fm)
#pragma unroll
    for (int rg = 0; rg < 4; ++rg) trow[fm][rg] = 0.f;
#pragma unroll
  for (int fm = 0; fm < 4; ++fm)
#pragma unroll
    for (int fn = 0; fn < 4; ++fn) {
      float ibn = ib[fn];
#pragma unroll
      for (int rg = 0; rg < 4; ++rg) {
        float g = acc[fm][fn][rg];
        float d2 = fmaf(-2.f, g, a2[fm][rg] + b2[fn]);
        float d = sqrtf(fmaxf(d2, 0.f));
        float sim = fmaxf(g, 0.f) * ia[fm][rg] * ibn * exp2f(d * nim);
        if (diag) {
          int il = wi * 64 + fm * 16 + g16 * 4 + rg;
          int jl = wn * 64 + fn * 16 + l15;
          if (il == jl) sim = 0.f;
        }
        ssum += sim;
        trow[fm][rg] = fmaf(sim, zj[fn], trow[fm][rg]);
        tcol[fn] = fmaf(sim, zi[fm][rg], tcol[fn]);
      }
    }
#pragma unroll
  for (int fm = 0; fm < 4; ++fm)
#pragma unroll
    for (int rg = 0; rg < 4; ++rg) {
      float v = trow[fm][rg];
#pragma unroll
      for (int o = 8; o; o >>= 1) v += __shfl_xor(v, o);
      if (l15 == 0) atomicAdd(&tfull[i0 + wi * 64 + fm * 16 + g16 * 4 + rg], v);
    }
  if (!diag) {
#pragma unroll
    for (int fn = 0; fn < 4; ++fn) {
      float v = tcol[fn];
      v += __shfl_xor(v, 16);
      v += __shfl_xor(v, 32);
      if (g16 == 0) atomicAdd(&tfull[j0 + wn * 64 + fn * 16 + l15], v);
    }
  }
  ssum = wave_sum(ssum);
  if (lane == 0) red[wave] = ssum;
  __syncthreads();
  if (t == 0) spart[blk] = ((red[0] + red[1]) + (red[2] + red[3])) * (diag ? 1.f : 2.f);
  tpart[(size_t)blk * NC + t] = tfull[t];
  tpart[(size_t)blk * NC + t + 256] = tfull[t + 256];

  // ---- last block of this batch runs the MLP (threadfence reduction idiom) ----
  __threadfence();
  if (t == 0) {
    int old = atomicAdd(&cnt[b], 1);
    lastFlag = (old == NTASK - 1);
  }
  __syncthreads();
  if (!lastFlag) return;
  __threadfence();  // acquire: see other blocks' tpart/spart
  float* chL = tfull;  // reuse LDS
  float S = 0.f;
#pragma unroll
  for (int k = 0; k < NTASK; ++k) S += spart[b * NTASK + k];
  float invS = 1.f / (S + 1e-10f);
  float t0 = 0.f, t1 = 0.f;
#pragma unroll
  for (int j = 0; j < NTASK; ++j) {
    t0 += tpart[((size_t)b * NTASK + j) * NC + t];
    t1 += tpart[((size_t)b * NTASK + j) * NC + t + 256];
  }
  float lm0 = zL[t] * t0 * invS;
  float lm1 = zL[t + 256] * t1 * invS;
  __syncthreads();
  float q3 = wave_sum(lm0 + lm1);
  if (lane == 0) red[wave] = q3;
  __syncthreads();
  float m = ((red[0] + red[1]) + (red[2] + red[3])) * (1.f / 512.f);
  float d0 = lm0 - m, d1 = lm1 - m;
  __syncthreads();
  float q4 = wave_sum(d0 * d0 + d1 * d1);
  if (lane == 0) red[wave] = q4;
  __syncthreads();
  float sd = sqrtf(((red[0] + red[1]) + (red[2] + red[3])) * (1.f / 511.f)) + 1e-12f;
  chL[t] = d0 / sd;
  chL[t + 256] = d1 / sd;
  __syncthreads();
  int k = t >> 3, p = t & 7;
  const float* wrow = wD + k * NC + p * 64;
  const float* cp = chL + p * 64;
  float hp = 0.f;
#pragma unroll
  for (int i = 0; i < 64; ++i) hp += wrow[i] * cp[i];
#pragma unroll
  for (int o = 4; o; o >>= 1) hp += __shfl_xor(hp, o);
  if (p == 0) hL[k] = fmaxf(hp + bD[k], 0.f);
  __syncthreads();
#pragma unroll
  for (int u = 0; u < 2; ++u) {
    int c = t + u * 256;
    const float* wrU = wU + c * NR;
    float att = bU[c];
#pragma unroll
    for (int kk = 0; kk < NR; ++kk) att += hL[kk] * wrU[kk];
    scl[b * NC + c] = 1.f / (1.f + __expf(-att));
  }
}

// ---------------- K4: out = x * scale (NT store; x expected L3-resident) ----------------
__global__ __launch_bounds__(256) void scale_kernel(const float* __restrict__ x,
                                                    const float* __restrict__ scl,
                                                    float* __restrict__ out) {
  unsigned idx = blockIdx.x * 256u + threadIdx.x;  // float4 index, total 6422528
  unsigned row = idx / 196u;                       // b*512 + c
  float s = scl[row];
  f32x4 v = ((const f32x4*)x)[idx];
  v *= s;
  __builtin_nontemporal_store(v, ((f32x4*)out) + idx);
}

extern "C" void kernel_launch(void* const* d_in, const int* in_sizes, int n_in,
                              void* d_out, int out_size, void* d_ws, size_t ws_size,
                              hipStream_t stream) {
  const float* x = (const float*)d_in[0];
  const float* wD = (const float*)d_in[1];
  const float* bD = (const float*)d_in[2];
  const float* wU = (const float*)d_in[3];
  const float* bU = (const float*)d_in[4];
  float* out = (float*)d_out;
  char* ws = (char*)d_ws;

  __hip_bfloat16* xap = (__hip_bfloat16*)ws;  // 64*512*64*2 = 4 MB
  float* fbase = (float*)(ws + (size_t)NB * NC * KP * 2);
  float* wbuf = fbase;                   // 32768 f32
  float* gap = wbuf + NB * NC;           // 32768
  float* dpart = gap + NB * NC;          // 640
  float* spart = dpart + NB * NTASK;     // 640
  float* tpart = spart + NB * NTASK;     // 64*10*512 = 327680
  float* scl = tpart + NB * NTASK * NC;  // 32768
  int* cnt = (int*)(scl + NB * NC);      // 64 ints

  hipLaunchKernelGGL(pool_kernel, dim3(NB * NC / 4), dim3(256), 0, stream, x, xap, wbuf, gap, cnt);
  hipLaunchKernelGGL(meand_kernel, dim3(NB * NTASK), dim3(256), 0, stream, xap, wbuf, dpart);
  hipLaunchKernelGGL(sim_kernel, dim3(NB * NTASK), dim3(256), 0, stream, xap, wbuf, gap, dpart,
                     tpart, spart, wD, bD, wU, bU, scl, cnt);
  hipLaunchKernelGGL(scale_kernel, dim3(25088), dim3(256), 0, stream, x, scl, out);
}

// Round 7
// 116.127 us; speedup vs baseline: 2.5237x; 1.6539x over previous
//
#include <hip/hip_runtime.h>
#include <hip/hip_bf16.h>
#include <stdint.h>

#define NB 64
#define NC 512
#define NHW 784
#define NK 49
#define KP 64
#define NR 32
#define NTASK 10

typedef short sh8 __attribute__((ext_vector_type(8)));
typedef float f32x4 __attribute__((ext_vector_type(4)));
typedef int v4i __attribute__((ext_vector_type(4)));

__device__ __forceinline__ float wave_sum(float v) {
#pragma unroll
  for (int o = 32; o; o >>= 1) v += __shfl_xor(v, o);
  return v;
}

__device__ __forceinline__ void task_decode(int s, int& ti, int& tj) {
  // upper-triangle enumeration: (0,0)(0,1)(0,2)(0,3)(1,1)(1,2)(1,3)(2,2)(2,3)(3,3)
  if (s < 4) { ti = 0; tj = s; }
  else if (s < 7) { ti = 1; tj = s - 3; }
  else if (s < 9) { ti = 2; tj = s - 5; }
  else { ti = 3; tj = 3; }
}

// ---------------- K1: pool, fully-coalesced loads + LDS bin accumulation ----------------
// wave = one row (784 floats = 196 float4). float4 f -> bin (f/28)*7 + f%7.
__global__ __launch_bounds__(256) void pool_kernel(const float* __restrict__ x,
                                                   __hip_bfloat16* __restrict__ xap,
                                                   float* __restrict__ wbuf,
                                                   float* __restrict__ gap) {
  __shared__ float bins[4][64];
  int t = threadIdx.x, wid = t >> 6, lane = t & 63;
  int row = blockIdx.x * 4 + wid;  // b*512 + c
  const f32x4* xr = (const f32x4*)(x + (size_t)row * NHW);
  bins[wid][lane] = 0.f;
  __syncthreads();
#pragma unroll
  for (int i = 0; i < 3; ++i) {
    int f = i * 64 + lane;
    f32x4 v = xr[f];
    float s = (v.x + v.y) + (v.z + v.w);
    int bi = (f / 28) * 7 + f % 7;
    atomicAdd(&bins[wid][bi], s);
  }
  if (lane < 4) {
    int f = 192 + lane;
    f32x4 v = xr[f];
    float s = (v.x + v.y) + (v.z + v.w);
    int bi = (f / 28) * 7 + f % 7;
    atomicAdd(&bins[wid][bi], s);
  }
  __syncthreads();
  float bin = bins[wid][lane] * 0.0625f;  // lanes>=49 stay 0 (pad)
  float s1 = wave_sum(bin);
  float s2 = wave_sum(bin * bin);
  xap[(size_t)row * KP + lane] = __float2bfloat16(bin);
  if (lane == 0) {
    wbuf[row] = sqrtf(s2);         // per-channel L2 norm
    gap[row] = s1 * (1.f / 49.f);  // == mean over 784
  }
}

// ---------------- K2: pass A — weighted sum of d per (batch, triangle-tile) ----------------
__global__ __launch_bounds__(256) void meand_kernel(const __hip_bfloat16* __restrict__ xap,
                                                    const float* __restrict__ wbuf,
                                                    float* __restrict__ dpart) {
  __shared__ __align__(16) __hip_bfloat16 Ab[128 * KP];
  __shared__ __align__(16) __hip_bfloat16 Bb[128 * KP];
  __shared__ float wiL[128], wjL[128];
  __shared__ float red[4];
  int blk = blockIdx.x;
  int b = blk / NTASK, s = blk - b * NTASK;
  int ti, tj;
  task_decode(s, ti, tj);
  bool diag = (ti == tj);
  int i0 = ti * 128, j0 = tj * 128;
  int t = threadIdx.x;
  const v4i* ga = (const v4i*)(xap + ((size_t)b * NC + i0) * KP);
  const v4i* gb = (const v4i*)(xap + ((size_t)b * NC + j0) * KP);
  v4i* la = (v4i*)Ab;
  v4i* lb = (v4i*)Bb;
#pragma unroll
  for (int q = 0; q < 4; ++q) {
    int cid = q * 256 + t;
    int r = cid >> 3, c = cid & 7;
    int dst = (r << 3) | (c ^ (r & 7));
    la[dst] = ga[cid];
    lb[dst] = gb[cid];
  }
  if (t < 128) {
    wiL[t] = wbuf[b * NC + i0 + t];
    wjL[t] = wbuf[b * NC + j0 + t];
  }
  __syncthreads();
  int lane = t & 63, wave = t >> 6;
  int wi = wave >> 1, wn = wave & 1;
  int l15 = lane & 15, g16 = lane >> 4;
  sh8 af[4][2], bfr[4][2];
#pragma unroll
  for (int f = 0; f < 4; ++f) {
#pragma unroll
    for (int ks = 0; ks < 2; ++ks) {
      int ra = wi * 64 + f * 16 + l15;
      int rb = wn * 64 + f * 16 + l15;
      int cg2 = ks * 4 + g16;
      af[f][ks] = __builtin_bit_cast(sh8, ((const v4i*)Ab)[(ra << 3) | (cg2 ^ (ra & 7))]);
      bfr[f][ks] = __builtin_bit_cast(sh8, ((const v4i*)Bb)[(rb << 3) | (cg2 ^ (rb & 7))]);
    }
  }
  f32x4 acc[4][4];
#pragma unroll
  for (int fm = 0; fm < 4; ++fm)
#pragma unroll
    for (int fn = 0; fn < 4; ++fn) acc[fm][fn] = (f32x4){0.f, 0.f, 0.f, 0.f};
#pragma unroll
  for (int ks = 0; ks < 2; ++ks)
#pragma unroll
    for (int fm = 0; fm < 4; ++fm)
#pragma unroll
      for (int fn = 0; fn < 4; ++fn)
        acc[fm][fn] =
            __builtin_amdgcn_mfma_f32_16x16x32_bf16(af[fm][ks], bfr[fn][ks], acc[fm][fn], 0, 0, 0);
  float a2[4][4], b2[4];
#pragma unroll
  for (int fm = 0; fm < 4; ++fm)
#pragma unroll
    for (int rg = 0; rg < 4; ++rg) {
      float a = wiL[wi * 64 + fm * 16 + g16 * 4 + rg];
      a2[fm][rg] = a * a;
    }
#pragma unroll
  for (int fn = 0; fn < 4; ++fn) {
    float w = wjL[wn * 64 + fn * 16 + l15];
    b2[fn] = w * w;
  }
  float dsum = 0.f;
#pragma unroll
  for (int fm = 0; fm < 4; ++fm)
#pragma unroll
    for (int fn = 0; fn < 4; ++fn)
#pragma unroll
      for (int rg = 0; rg < 4; ++rg) {
        float d2 = fmaf(-2.f, acc[fm][fn][rg], a2[fm][rg] + b2[fn]);
        dsum += sqrtf(fmaxf(d2, 0.f));
      }
  dsum = wave_sum(dsum);
  if (lane == 0) red[wave] = dsum;
  __syncthreads();
  if (t == 0) dpart[blk] = ((red[0] + red[1]) + (red[2] + red[3])) * (diag ? 1.f : 2.f);
}

// ---------------- K3: pass B — sim on triangle tiles; rows AND cols of t; weighted S ----
__global__ __launch_bounds__(256) void sim_kernel(const __hip_bfloat16* __restrict__ xap,
                                                  const float* __restrict__ wbuf,
                                                  const float* __restrict__ gap,
                                                  const float* __restrict__ dpart,
                                                  float* __restrict__ tpart,
                                                  float* __restrict__ spart) {
  __shared__ __align__(16) __hip_bfloat16 Ab[128 * KP];
  __shared__ __align__(16) __hip_bfloat16 Bb[128 * KP];
  __shared__ float wiL[128], wjL[128], zL[NC], tfull[NC];
  __shared__ float red[4];
  int blk = blockIdx.x;
  int b = blk / NTASK, s = blk - b * NTASK;
  int ti, tj;
  task_decode(s, ti, tj);
  bool diag = (ti == tj);
  int i0 = ti * 128, j0 = tj * 128;
  int t = threadIdx.x;
  int lane = t & 63, wave = t >> 6;
  float dsb = 0.f;
#pragma unroll
  for (int k = 0; k < NTASK; ++k) dsb += dpart[b * NTASK + k];
  float nim = -1.44269504f / (dsb * (1.f / 262144.f) + 1e-10f);  // -log2e / mean_d
  const v4i* ga = (const v4i*)(xap + ((size_t)b * NC + i0) * KP);
  const v4i* gb = (const v4i*)(xap + ((size_t)b * NC + j0) * KP);
  v4i* la = (v4i*)Ab;
  v4i* lb = (v4i*)Bb;
#pragma unroll
  for (int q = 0; q < 4; ++q) {
    int cid = q * 256 + t;
    int r = cid >> 3, c = cid & 7;
    int dst = (r << 3) | (c ^ (r & 7));
    la[dst] = ga[cid];
    lb[dst] = gb[cid];
  }
  if (t < 128) {
    wiL[t] = wbuf[b * NC + i0 + t];
    wjL[t] = wbuf[b * NC + j0 + t];
  }
  tfull[t] = 0.f;
  tfull[t + 256] = 0.f;
  // z = (gap - mu)/std (unbiased), bitwise identical wherever recomputed
  float g0 = gap[b * NC + t], g1 = gap[b * NC + t + 256];
  float s1 = wave_sum(g0 + g1);
  if (lane == 0) red[wave] = s1;
  __syncthreads();
  float mu = ((red[0] + red[1]) + (red[2] + red[3])) * (1.f / 512.f);
  float e0 = g0 - mu, e1 = g1 - mu;
  __syncthreads();
  float vv = wave_sum(e0 * e0 + e1 * e1);
  if (lane == 0) red[wave] = vv;
  __syncthreads();
  float inv_sd = 1.f / sqrtf(((red[0] + red[1]) + (red[2] + red[3])) * (1.f / 511.f));
  zL[t] = e0 * inv_sd;
  zL[t + 256] = e1 * inv_sd;
  __syncthreads();
  int wi = wave >> 1, wn = wave & 1;
  int l15 = lane & 15, g16 = lane >> 4;
  sh8 af[4][2], bfr[4][2];
#pragma unroll
  for (int f = 0; f < 4; ++f) {
#pragma unroll
    for (int ks = 0; ks < 2; ++ks) {
      int ra = wi * 64 + f * 16 + l15;
      int rb = wn * 64 + f * 16 + l15;
      int cg2 = ks * 4 + g16;
      af[f][ks] = __builtin_bit_cast(sh8, ((const v4i*)Ab)[(ra << 3) | (cg2 ^ (ra & 7))]);
      bfr[f][ks] = __builtin_bit_cast(sh8, ((const v4i*)Bb)[(rb << 3) | (cg2 ^ (rb & 7))]);
    }
  }
  f32x4 acc[4][4];
#pragma unroll
  for (int fm = 0; fm < 4; ++fm)
#pragma unroll
    for (int fn = 0; fn < 4; ++fn) acc[fm][fn] = (f32x4){0.f, 0.f, 0.f, 0.f};
#pragma unroll
  for (int ks = 0; ks < 2; ++ks)
#pragma unroll
    for (int fm = 0; fm < 4; ++fm)
#pragma unroll
      for (int fn = 0; fn < 4; ++fn)
        acc[fm][fn] =
            __builtin_amdgcn_mfma_f32_16x16x32_bf16(af[fm][ks], bfr[fn][ks], acc[fm][fn], 0, 0, 0);
  float a2[4][4], ia[4][4], zi[4][4];
#pragma unroll
  for (int fm = 0; fm < 4; ++fm)
#pragma unroll
    for (int rg = 0; rg < 4; ++rg) {
      int il = wi * 64 + fm * 16 + g16 * 4 + rg;
      float a = wiL[il];
      a2[fm][rg] = a * a;
      ia[fm][rg] = 1.f / fmaxf(a, 1e-7f);
      zi[fm][rg] = zL[i0 + il];
    }
  float b2[4], ib[4], zj[4];
#pragma unroll
  for (int fn = 0; fn < 4; ++fn) {
    int jl = wn * 64 + fn * 16 + l15;
    float w = wjL[jl];
    b2[fn] = w * w;
    ib[fn] = 1.f / fmaxf(w, 1e-7f);
    zj[fn] = zL[j0 + jl];
  }
  float ssum = 0.f;
  float trow[4][4];
  float tcol[4] = {0.f, 0.f, 0.f, 0.f};
#pragma unroll
  for (int fm = 0; fm < 4; ++fm)
#pragma unroll
    for (int rg = 0; rg < 4; ++rg) trow[fm][rg] = 0.f;
#pragma unroll
  for (int fm = 0; fm < 4; ++fm)
#pragma unroll
    for (int fn = 0; fn < 4; ++fn) {
      float ibn = ib[fn];
#pragma unroll
      for (int rg = 0; rg < 4; ++rg) {
        float g = acc[fm][fn][rg];
        float d2 = fmaf(-2.f, g, a2[fm][rg] + b2[fn]);
        float d = sqrtf(fmaxf(d2, 0.f));
        float sim = fmaxf(g, 0.f) * ia[fm][rg] * ibn * exp2f(d * nim);
        if (diag) {
          int il = wi * 64 + fm * 16 + g16 * 4 + rg;
          int jl = wn * 64 + fn * 16 + l15;
          if (il == jl) sim = 0.f;
        }
        ssum += sim;
        trow[fm][rg] = fmaf(sim, zj[fn], trow[fm][rg]);
        tcol[fn] = fmaf(sim, zi[fm][rg], tcol[fn]);
      }
    }
  // row contributions: reduce over l15 (j within 16-group)
#pragma unroll
  for (int fm = 0; fm < 4; ++fm)
#pragma unroll
    for (int rg = 0; rg < 4; ++rg) {
      float v = trow[fm][rg];
#pragma unroll
      for (int o = 8; o; o >>= 1) v += __shfl_xor(v, o);
      if (l15 == 0) atomicAdd(&tfull[i0 + wi * 64 + fm * 16 + g16 * 4 + rg], v);
    }
  // column contributions (off-diag tiles only)
  if (!diag) {
#pragma unroll
    for (int fn = 0; fn < 4; ++fn) {
      float v = tcol[fn];
      v += __shfl_xor(v, 16);
      v += __shfl_xor(v, 32);
      if (g16 == 0) atomicAdd(&tfull[j0 + wn * 64 + fn * 16 + l15], v);
    }
  }
  ssum = wave_sum(ssum);
  if (lane == 0) red[wave] = ssum;
  __syncthreads();
  if (t == 0) spart[blk] = ((red[0] + red[1]) + (red[2] + red[3])) * (diag ? 1.f : 2.f);
  tpart[(size_t)blk * NC + t] = tfull[t];
  tpart[(size_t)blk * NC + t + 256] = tfull[t + 256];
}

// ---------------- K4: per-batch z, local_mi -> normalize -> MLP -> sigmoid scale ----------
__global__ __launch_bounds__(256) void mlp_kernel(const float* __restrict__ gap,
                                                  const float* __restrict__ tpart,
                                                  const float* __restrict__ spart,
                                                  const float* __restrict__ wD,
                                                  const float* __restrict__ bD,
                                                  const float* __restrict__ wU,
                                                  const float* __restrict__ bU,
                                                  float* __restrict__ scl) {
  __shared__ float red[4];
  __shared__ float chL[NC];
  __shared__ float hL[NR];
  int b = blockIdx.x, t = threadIdx.x;
  int lane = t & 63, wid = t >> 6;
  float S = 0.f;
#pragma unroll
  for (int k = 0; k < NTASK; ++k) S += spart[b * NTASK + k];
  float invS = 1.f / (S + 1e-10f);
  float t0 = 0.f, t1 = 0.f;
#pragma unroll
  for (int j = 0; j < NTASK; ++j) {
    t0 += tpart[((size_t)b * NTASK + j) * NC + t];
    t1 += tpart[((size_t)b * NTASK + j) * NC + t + 256];
  }
  // z from gap (identical arithmetic to sim_kernel)
  float g0 = gap[b * NC + t], g1 = gap[b * NC + t + 256];
  float s1 = wave_sum(g0 + g1);
  if (lane == 0) red[wid] = s1;
  __syncthreads();
  float mu = ((red[0] + red[1]) + (red[2] + red[3])) * (1.f / 512.f);
  float e0 = g0 - mu, e1 = g1 - mu;
  __syncthreads();
  float vv = wave_sum(e0 * e0 + e1 * e1);
  if (lane == 0) red[wid] = vv;
  __syncthreads();
  float inv_sd = 1.f / sqrtf(((red[0] + red[1]) + (red[2] + red[3])) * (1.f / 511.f));
  float lm0 = e0 * inv_sd * t0 * invS;
  float lm1 = e1 * inv_sd * t1 * invS;
  __syncthreads();
  float s2 = wave_sum(lm0 + lm1);
  if (lane == 0) red[wid] = s2;
  __syncthreads();
  float m = ((red[0] + red[1]) + (red[2] + red[3])) * (1.f / 512.f);
  float d0 = lm0 - m, d1 = lm1 - m;
  __syncthreads();
  float v2 = wave_sum(d0 * d0 + d1 * d1);
  if (lane == 0) red[wid] = v2;
  __syncthreads();
  float sd = sqrtf(((red[0] + red[1]) + (red[2] + red[3])) * (1.f / 511.f)) + 1e-12f;
  chL[t] = d0 / sd;
  chL[t + 256] = d1 / sd;
  __syncthreads();
  int k = t >> 3, p = t & 7;
  const float* wrow = wD + k * NC + p * 64;
  const float* cp = chL + p * 64;
  float hp = 0.f;
#pragma unroll
  for (int i = 0; i < 64; ++i) hp += wrow[i] * cp[i];
#pragma unroll
  for (int o = 4; o; o >>= 1) hp += __shfl_xor(hp, o);
  if (p == 0) hL[k] = fmaxf(hp + bD[k], 0.f);
  __syncthreads();
#pragma unroll
  for (int u = 0; u < 2; ++u) {
    int c = t + u * 256;
    const float* wrU = wU + c * NR;
    float att = bU[c];
#pragma unroll
    for (int kk = 0; kk < NR; ++kk) att += hL[kk] * wrU[kk];
    scl[b * NC + c] = 1.f / (1.f + __expf(-att));
  }
}

// ---------------- K5: out = x * scale (x from L3; NT store for out) ----------------
__global__ __launch_bounds__(256) void scale_kernel(const float* __restrict__ x,
                                                    const float* __restrict__ scl,
                                                    float* __restrict__ out) {
  unsigned idx = blockIdx.x * 256u + threadIdx.x;  // float4 index, total 6422528
  unsigned row = idx / 196u;                       // b*512 + c
  float s = scl[row];
  f32x4 v = ((const f32x4*)x)[idx];
  v *= s;
  __builtin_nontemporal_store(v, ((f32x4*)out) + idx);
}

extern "C" void kernel_launch(void* const* d_in, const int* in_sizes, int n_in,
                              void* d_out, int out_size, void* d_ws, size_t ws_size,
                              hipStream_t stream) {
  const float* x = (const float*)d_in[0];
  const float* wD = (const float*)d_in[1];
  const float* bD = (const float*)d_in[2];
  const float* wU = (const float*)d_in[3];
  const float* bU = (const float*)d_in[4];
  float* out = (float*)d_out;
  char* ws = (char*)d_ws;

  __hip_bfloat16* xap = (__hip_bfloat16*)ws;  // 64*512*64*2 = 4 MB
  float* fbase = (float*)(ws + (size_t)NB * NC * KP * 2);
  float* wbuf = fbase;                   // 32768 f32
  float* gap = wbuf + NB * NC;           // 32768
  float* dpart = gap + NB * NC;          // 640
  float* spart = dpart + NB * NTASK;     // 640
  float* tpart = spart + NB * NTASK;     // 64*10*512 = 327680
  float* scl = tpart + NB * NTASK * NC;  // 32768

  hipLaunchKernelGGL(pool_kernel, dim3(NB * NC / 4), dim3(256), 0, stream, x, xap, wbuf, gap);
  hipLaunchKernelGGL(meand_kernel, dim3(NB * NTASK), dim3(256), 0, stream, xap, wbuf, dpart);
  hipLaunchKernelGGL(sim_kernel, dim3(NB * NTASK), dim3(256), 0, stream, xap, wbuf, gap, dpart,
                     tpart, spart);
  hipLaunchKernelGGL(mlp_kernel, dim3(NB), dim3(256), 0, stream, gap, tpart, spart, wD, bD, wU, bU,
                     scl);
  hipLaunchKernelGGL(scale_kernel, dim3(25088), dim3(256), 0, stream, x, scl, out);
}

// Round 8
// 92.832 us; speedup vs baseline: 3.1570x; 1.2509x over previous
//
#include <hip/hip_runtime.h>
#include <hip/hip_bf16.h>
#include <stdint.h>

#define NB 64
#define NC 512
#define NHW 784
#define NK 49
#define KP 64
#define NR 32
#define NTASK 10

typedef short sh8 __attribute__((ext_vector_type(8)));
typedef float f32x4 __attribute__((ext_vector_type(4)));
typedef int v4i __attribute__((ext_vector_type(4)));

__device__ __forceinline__ float wave_sum(float v) {
#pragma unroll
  for (int o = 32; o; o >>= 1) v += __shfl_xor(v, o);
  return v;
}

__device__ __forceinline__ void task_decode(int s, int& ti, int& tj) {
  // upper-triangle enumeration: (0,0)(0,1)(0,2)(0,3)(1,1)(1,2)(1,3)(2,2)(2,3)(3,3)
  if (s < 4) { ti = 0; tj = s; }
  else if (s < 7) { ti = 1; tj = s - 3; }
  else if (s < 9) { ti = 2; tj = s - 5; }
  else { ti = 3; tj = 3; }
}

// ---------------- K1: pool — coalesced loads, atomic-free LDS scatter/gather ----------------
// wave = one row (784 floats = 196 float4). float4 f = r*7 + c4 (r=0..27 spatial row,
// c4=cols 4c4..4c4+3). bin(br,bc) = sf[28br+bc] + sf[+7] + sf[+14] + sf[+21].
__global__ __launch_bounds__(256) void pool_kernel(const float* __restrict__ x,
                                                   __hip_bfloat16* __restrict__ xap,
                                                   float* __restrict__ wbuf,
                                                   float* __restrict__ gap) {
  __shared__ float sf[4][196];
  int t = threadIdx.x, wid = t >> 6, lane = t & 63;
  int row = blockIdx.x * 4 + wid;  // b*512 + c
  const f32x4* xr = (const f32x4*)(x + (size_t)row * NHW);
  f32x4 v0 = xr[lane];
  f32x4 v1 = xr[lane + 64];
  f32x4 v2 = xr[lane + 128];
  sf[wid][lane] = (v0.x + v0.y) + (v0.z + v0.w);
  sf[wid][lane + 64] = (v1.x + v1.y) + (v1.z + v1.w);
  sf[wid][lane + 128] = (v2.x + v2.y) + (v2.z + v2.w);
  if (lane < 4) {
    f32x4 v3 = xr[lane + 192];
    sf[wid][lane + 192] = (v3.x + v3.y) + (v3.z + v3.w);
  }
  __syncthreads();
  float bin = 0.f;
  if (lane < NK) {
    int pr = lane / 7, pc = lane - pr * 7;
    int f0 = pr * 28 + pc;
    bin = ((sf[wid][f0] + sf[wid][f0 + 7]) + (sf[wid][f0 + 14] + sf[wid][f0 + 21])) * 0.0625f;
  }
  float s1 = wave_sum(bin);
  float s2 = wave_sum(bin * bin);
  xap[(size_t)row * KP + lane] = __float2bfloat16(bin);  // lanes>=49 write 0 pad
  if (lane == 0) {
    wbuf[row] = sqrtf(s2);         // per-channel L2 norm
    gap[row] = s1 * (1.f / 49.f);  // == mean over 784
  }
}

// ---------------- K2: pass A — weighted sum of d per (batch, triangle-tile) ----------------
__global__ __launch_bounds__(256) void meand_kernel(const __hip_bfloat16* __restrict__ xap,
                                                    const float* __restrict__ wbuf,
                                                    float* __restrict__ dpart) {
  __shared__ __align__(16) __hip_bfloat16 Ab[128 * KP];
  __shared__ __align__(16) __hip_bfloat16 Bb[128 * KP];
  __shared__ float wiL[128], wjL[128];
  __shared__ float red[4];
  int blk = blockIdx.x;
  int b = blk / NTASK, s = blk - b * NTASK;
  int ti, tj;
  task_decode(s, ti, tj);
  bool diag = (ti == tj);
  int i0 = ti * 128, j0 = tj * 128;
  int t = threadIdx.x;
  const v4i* ga = (const v4i*)(xap + ((size_t)b * NC + i0) * KP);
  const v4i* gb = (const v4i*)(xap + ((size_t)b * NC + j0) * KP);
  v4i* la = (v4i*)Ab;
  v4i* lb = (v4i*)Bb;
#pragma unroll
  for (int q = 0; q < 4; ++q) {
    int cid = q * 256 + t;
    int r = cid >> 3, c = cid & 7;
    int dst = (r << 3) | (c ^ (r & 7));
    la[dst] = ga[cid];
    lb[dst] = gb[cid];
  }
  if (t < 128) {
    wiL[t] = wbuf[b * NC + i0 + t];
    wjL[t] = wbuf[b * NC + j0 + t];
  }
  __syncthreads();
  int lane = t & 63, wave = t >> 6;
  int wi = wave >> 1, wn = wave & 1;
  int l15 = lane & 15, g16 = lane >> 4;
  sh8 af[4][2], bfr[4][2];
#pragma unroll
  for (int f = 0; f < 4; ++f) {
#pragma unroll
    for (int ks = 0; ks < 2; ++ks) {
      int ra = wi * 64 + f * 16 + l15;
      int rb = wn * 64 + f * 16 + l15;
      int cg2 = ks * 4 + g16;
      af[f][ks] = __builtin_bit_cast(sh8, ((const v4i*)Ab)[(ra << 3) | (cg2 ^ (ra & 7))]);
      bfr[f][ks] = __builtin_bit_cast(sh8, ((const v4i*)Bb)[(rb << 3) | (cg2 ^ (rb & 7))]);
    }
  }
  f32x4 acc[4][4];
#pragma unroll
  for (int fm = 0; fm < 4; ++fm)
#pragma unroll
    for (int fn = 0; fn < 4; ++fn) acc[fm][fn] = (f32x4){0.f, 0.f, 0.f, 0.f};
#pragma unroll
  for (int ks = 0; ks < 2; ++ks)
#pragma unroll
    for (int fm = 0; fm < 4; ++fm)
#pragma unroll
      for (int fn = 0; fn < 4; ++fn)
        acc[fm][fn] =
            __builtin_amdgcn_mfma_f32_16x16x32_bf16(af[fm][ks], bfr[fn][ks], acc[fm][fn], 0, 0, 0);
  float a2[4][4], b2[4];
#pragma unroll
  for (int fm = 0; fm < 4; ++fm)
#pragma unroll
    for (int rg = 0; rg < 4; ++rg) {
      float a = wiL[wi * 64 + fm * 16 + g16 * 4 + rg];
      a2[fm][rg] = a * a;
    }
#pragma unroll
  for (int fn = 0; fn < 4; ++fn) {
    float w = wjL[wn * 64 + fn * 16 + l15];
    b2[fn] = w * w;
  }
  float dsum = 0.f;
#pragma unroll
  for (int fm = 0; fm < 4; ++fm)
#pragma unroll
    for (int fn = 0; fn < 4; ++fn)
#pragma unroll
      for (int rg = 0; rg < 4; ++rg) {
        float d2 = fmaf(-2.f, acc[fm][fn][rg], a2[fm][rg] + b2[fn]);
        dsum += sqrtf(fmaxf(d2, 0.f));
      }
  dsum = wave_sum(dsum);
  if (lane == 0) red[wave] = dsum;
  __syncthreads();
  if (t == 0) dpart[blk] = ((red[0] + red[1]) + (red[2] + red[3])) * (diag ? 1.f : 2.f);
}

// ---------------- K3: pass B — sim on triangle tiles; rows AND cols of t; weighted S ----
__global__ __launch_bounds__(256) void sim_kernel(const __hip_bfloat16* __restrict__ xap,
                                                  const float* __restrict__ wbuf,
                                                  const float* __restrict__ gap,
                                                  const float* __restrict__ dpart,
                                                  float* __restrict__ tpart,
                                                  float* __restrict__ spart) {
  __shared__ __align__(16) __hip_bfloat16 Ab[128 * KP];
  __shared__ __align__(16) __hip_bfloat16 Bb[128 * KP];
  __shared__ float wiL[128], wjL[128], zL[NC], tfull[NC];
  __shared__ float red[4];
  int blk = blockIdx.x;
  int b = blk / NTASK, s = blk - b * NTASK;
  int ti, tj;
  task_decode(s, ti, tj);
  bool diag = (ti == tj);
  int i0 = ti * 128, j0 = tj * 128;
  int t = threadIdx.x;
  int lane = t & 63, wave = t >> 6;
  float dsb = 0.f;
#pragma unroll
  for (int k = 0; k < NTASK; ++k) dsb += dpart[b * NTASK + k];
  float nim = -1.44269504f / (dsb * (1.f / 262144.f) + 1e-10f);  // -log2e / mean_d
  const v4i* ga = (const v4i*)(xap + ((size_t)b * NC + i0) * KP);
  const v4i* gb = (const v4i*)(xap + ((size_t)b * NC + j0) * KP);
  v4i* la = (v4i*)Ab;
  v4i* lb = (v4i*)Bb;
#pragma unroll
  for (int q = 0; q < 4; ++q) {
    int cid = q * 256 + t;
    int r = cid >> 3, c = cid & 7;
    int dst = (r << 3) | (c ^ (r & 7));
    la[dst] = ga[cid];
    lb[dst] = gb[cid];
  }
  if (t < 128) {
    wiL[t] = wbuf[b * NC + i0 + t];
    wjL[t] = wbuf[b * NC + j0 + t];
  }
  tfull[t] = 0.f;
  tfull[t + 256] = 0.f;
  // z = (gap - mu)/std (unbiased), bitwise identical wherever recomputed
  float g0 = gap[b * NC + t], g1 = gap[b * NC + t + 256];
  float s1 = wave_sum(g0 + g1);
  if (lane == 0) red[wave] = s1;
  __syncthreads();
  float mu = ((red[0] + red[1]) + (red[2] + red[3])) * (1.f / 512.f);
  float e0 = g0 - mu, e1 = g1 - mu;
  __syncthreads();
  float vv = wave_sum(e0 * e0 + e1 * e1);
  if (lane == 0) red[wave] = vv;
  __syncthreads();
  float inv_sd = 1.f / sqrtf(((red[0] + red[1]) + (red[2] + red[3])) * (1.f / 511.f));
  zL[t] = e0 * inv_sd;
  zL[t + 256] = e1 * inv_sd;
  __syncthreads();
  int wi = wave >> 1, wn = wave & 1;
  int l15 = lane & 15, g16 = lane >> 4;
  sh8 af[4][2], bfr[4][2];
#pragma unroll
  for (int f = 0; f < 4; ++f) {
#pragma unroll
    for (int ks = 0; ks < 2; ++ks) {
      int ra = wi * 64 + f * 16 + l15;
      int rb = wn * 64 + f * 16 + l15;
      int cg2 = ks * 4 + g16;
      af[f][ks] = __builtin_bit_cast(sh8, ((const v4i*)Ab)[(ra << 3) | (cg2 ^ (ra & 7))]);
      bfr[f][ks] = __builtin_bit_cast(sh8, ((const v4i*)Bb)[(rb << 3) | (cg2 ^ (rb & 7))]);
    }
  }
  f32x4 acc[4][4];
#pragma unroll
  for (int fm = 0; fm < 4; ++fm)
#pragma unroll
    for (int fn = 0; fn < 4; ++fn) acc[fm][fn] = (f32x4){0.f, 0.f, 0.f, 0.f};
#pragma unroll
  for (int ks = 0; ks < 2; ++ks)
#pragma unroll
    for (int fm = 0; fm < 4; ++fm)
#pragma unroll
      for (int fn = 0; fn < 4; ++fn)
        acc[fm][fn] =
            __builtin_amdgcn_mfma_f32_16x16x32_bf16(af[fm][ks], bfr[fn][ks], acc[fm][fn], 0, 0, 0);
  float a2[4][4], ia[4][4], zi[4][4];
#pragma unroll
  for (int fm = 0; fm < 4; ++fm)
#pragma unroll
    for (int rg = 0; rg < 4; ++rg) {
      int il = wi * 64 + fm * 16 + g16 * 4 + rg;
      float a = wiL[il];
      a2[fm][rg] = a * a;
      ia[fm][rg] = 1.f / fmaxf(a, 1e-7f);
      zi[fm][rg] = zL[i0 + il];
    }
  float b2[4], ib[4], zj[4];
#pragma unroll
  for (int fn = 0; fn < 4; ++fn) {
    int jl = wn * 64 + fn * 16 + l15;
    float w = wjL[jl];
    b2[fn] = w * w;
    ib[fn] = 1.f / fmaxf(w, 1e-7f);
    zj[fn] = zL[j0 + jl];
  }
  float ssum = 0.f;
  float trow[4][4];
  float tcol[4] = {0.f, 0.f, 0.f, 0.f};
#pragma unroll
  for (int fm = 0; fm < 4; ++fm)
#pragma unroll
    for (int rg = 0; rg < 4; ++rg) trow[fm][rg] = 0.f;
#pragma unroll
  for (int fm = 0; fm < 4; ++fm)
#pragma unroll
    for (int fn = 0; fn < 4; ++fn) {
      float ibn = ib[fn];
#pragma unroll
      for (int rg = 0; rg < 4; ++rg) {
        float g = acc[fm][fn][rg];
        float d2 = fmaf(-2.f, g, a2[fm][rg] + b2[fn]);
        float d = sqrtf(fmaxf(d2, 0.f));
        float sim = fmaxf(g, 0.f) * ia[fm][rg] * ibn * exp2f(d * nim);
        if (diag) {
          int il = wi * 64 + fm * 16 + g16 * 4 + rg;
          int jl = wn * 64 + fn * 16 + l15;
          if (il == jl) sim = 0.f;
        }
        ssum += sim;
        trow[fm][rg] = fmaf(sim, zj[fn], trow[fm][rg]);
        tcol[fn] = fmaf(sim, zi[fm][rg], tcol[fn]);
      }
    }
  // row contributions: reduce over l15 (j within 16-group)
#pragma unroll
  for (int fm = 0; fm < 4; ++fm)
#pragma unroll
    for (int rg = 0; rg < 4; ++rg) {
      float v = trow[fm][rg];
#pragma unroll
      for (int o = 8; o; o >>= 1) v += __shfl_xor(v, o);
      if (l15 == 0) atomicAdd(&tfull[i0 + wi * 64 + fm * 16 + g16 * 4 + rg], v);
    }
  // column contributions (off-diag tiles only)
  if (!diag) {
#pragma unroll
    for (int fn = 0; fn < 4; ++fn) {
      float v = tcol[fn];
      v += __shfl_xor(v, 16);
      v += __shfl_xor(v, 32);
      if (g16 == 0) atomicAdd(&tfull[j0 + wn * 64 + fn * 16 + l15], v);
    }
  }
  ssum = wave_sum(ssum);
  if (lane == 0) red[wave] = ssum;
  __syncthreads();
  if (t == 0) spart[blk] = ((red[0] + red[1]) + (red[2] + red[3])) * (diag ? 1.f : 2.f);
  tpart[(size_t)blk * NC + t] = tfull[t];
  tpart[(size_t)blk * NC + t + 256] = tfull[t + 256];
}

// ---------------- K4: per-batch z, local_mi -> normalize -> MLP -> sigmoid scale ----------
__global__ __launch_bounds__(256) void mlp_kernel(const float* __restrict__ gap,
                                                  const float* __restrict__ tpart,
                                                  const float* __restrict__ spart,
                                                  const float* __restrict__ wD,
                                                  const float* __restrict__ bD,
                                                  const float* __restrict__ wU,
                                                  const float* __restrict__ bU,
                                                  float* __restrict__ scl) {
  __shared__ float red[4];
  __shared__ float chL[NC];
  __shared__ float hL[NR];
  int b = blockIdx.x, t = threadIdx.x;
  int lane = t & 63, wid = t >> 6;
  float S = 0.f;
#pragma unroll
  for (int k = 0; k < NTASK; ++k) S += spart[b * NTASK + k];
  float invS = 1.f / (S + 1e-10f);
  float t0 = 0.f, t1 = 0.f;
#pragma unroll
  for (int j = 0; j < NTASK; ++j) {
    t0 += tpart[((size_t)b * NTASK + j) * NC + t];
    t1 += tpart[((size_t)b * NTASK + j) * NC + t + 256];
  }
  // z from gap (identical arithmetic to sim_kernel)
  float g0 = gap[b * NC + t], g1 = gap[b * NC + t + 256];
  float s1 = wave_sum(g0 + g1);
  if (lane == 0) red[wid] = s1;
  __syncthreads();
  float mu = ((red[0] + red[1]) + (red[2] + red[3])) * (1.f / 512.f);
  float e0 = g0 - mu, e1 = g1 - mu;
  __syncthreads();
  float vv = wave_sum(e0 * e0 + e1 * e1);
  if (lane == 0) red[wid] = vv;
  __syncthreads();
  float inv_sd = 1.f / sqrtf(((red[0] + red[1]) + (red[2] + red[3])) * (1.f / 511.f));
  float lm0 = e0 * inv_sd * t0 * invS;
  float lm1 = e1 * inv_sd * t1 * invS;
  __syncthreads();
  float s2 = wave_sum(lm0 + lm1);
  if (lane == 0) red[wid] = s2;
  __syncthreads();
  float m = ((red[0] + red[1]) + (red[2] + red[3])) * (1.f / 512.f);
  float d0 = lm0 - m, d1 = lm1 - m;
  __syncthreads();
  float v2 = wave_sum(d0 * d0 + d1 * d1);
  if (lane == 0) red[wid] = v2;
  __syncthreads();
  float sd = sqrtf(((red[0] + red[1]) + (red[2] + red[3])) * (1.f / 511.f)) + 1e-12f;
  chL[t] = d0 / sd;
  chL[t + 256] = d1 / sd;
  __syncthreads();
  int k = t >> 3, p = t & 7;
  const float* wrow = wD + k * NC + p * 64;
  const float* cp = chL + p * 64;
  float hp = 0.f;
#pragma unroll
  for (int i = 0; i < 64; ++i) hp += wrow[i] * cp[i];
#pragma unroll
  for (int o = 4; o; o >>= 1) hp += __shfl_xor(hp, o);
  if (p == 0) hL[k] = fmaxf(hp + bD[k], 0.f);
  __syncthreads();
#pragma unroll
  for (int u = 0; u < 2; ++u) {
    int c = t + u * 256;
    const float* wrU = wU + c * NR;
    float att = bU[c];
#pragma unroll
    for (int kk = 0; kk < NR; ++kk) att += hL[kk] * wrU[kk];
    scl[b * NC + c] = 1.f / (1.f + __expf(-att));
  }
}

// ---------------- K5: out = x * scale (x from L3; NT store for out) ----------------
__global__ __launch_bounds__(256) void scale_kernel(const float* __restrict__ x,
                                                    const float* __restrict__ scl,
                                                    float* __restrict__ out) {
  unsigned idx = blockIdx.x * 256u + threadIdx.x;  // float4 index, total 6422528
  unsigned row = idx / 196u;                       // b*512 + c
  float s = scl[row];
  f32x4 v = ((const f32x4*)x)[idx];
  v *= s;
  __builtin_nontemporal_store(v, ((f32x4*)out) + idx);
}

extern "C" void kernel_launch(void* const* d_in, const int* in_sizes, int n_in,
                              void* d_out, int out_size, void* d_ws, size_t ws_size,
                              hipStream_t stream) {
  const float* x = (const float*)d_in[0];
  const float* wD = (const float*)d_in[1];
  const float* bD = (const float*)d_in[2];
  const float* wU = (const float*)d_in[3];
  const float* bU = (const float*)d_in[4];
  float* out = (float*)d_out;
  char* ws = (char*)d_ws;

  __hip_bfloat16* xap = (__hip_bfloat16*)ws;  // 64*512*64*2 = 4 MB
  float* fbase = (float*)(ws + (size_t)NB * NC * KP * 2);
  float* wbuf = fbase;                   // 32768 f32
  float* gap = wbuf + NB * NC;           // 32768
  float* dpart = gap + NB * NC;          // 640
  float* spart = dpart + NB * NTASK;     // 640
  float* tpart = spart + NB * NTASK;     // 64*10*512 = 327680
  float* scl = tpart + NB * NTASK * NC;  // 32768

  hipLaunchKernelGGL(pool_kernel, dim3(NB * NC / 4), dim3(256), 0, stream, x, xap, wbuf, gap);
  hipLaunchKernelGGL(meand_kernel, dim3(NB * NTASK), dim3(256), 0, stream, xap, wbuf, dpart);
  hipLaunchKernelGGL(sim_kernel, dim3(NB * NTASK), dim3(256), 0, stream, xap, wbuf, gap, dpart,
                     tpart, spart);
  hipLaunchKernelGGL(mlp_kernel, dim3(NB), dim3(256), 0, stream, gap, tpart, spart, wD, bD, wU, bU,
                     scl);
  hipLaunchKernelGGL(scale_kernel, dim3(25088), dim3(256), 0, stream, x, scl, out);
}

// Round 9
// 82.358 us; speedup vs baseline: 3.5585x; 1.1272x over previous
//
#include <hip/hip_runtime.h>
#include <hip/hip_bf16.h>
#include <stdint.h>

#define NB 64
#define NC 512
#define NHW 784
#define NK 49
#define KP 64
#define NR 32
#define NTASK 10

typedef short sh8 __attribute__((ext_vector_type(8)));
typedef float f32x4 __attribute__((ext_vector_type(4)));
typedef int v4i __attribute__((ext_vector_type(4)));

__device__ __forceinline__ float wave_sum(float v) {
#pragma unroll
  for (int o = 32; o; o >>= 1) v += __shfl_xor(v, o);
  return v;
}

__device__ __forceinline__ void task_decode(int s, int& ti, int& tj) {
  // upper-triangle enumeration: (0,0)(0,1)(0,2)(0,3)(1,1)(1,2)(1,3)(2,2)(2,3)(3,3)
  if (s < 4) { ti = 0; tj = s; }
  else if (s < 7) { ti = 1; tj = s - 3; }
  else if (s < 9) { ti = 2; tj = s - 5; }
  else { ti = 3; tj = 3; }
}

// ---------------- K1: pool — coalesced loads, atomic-free LDS scatter/gather ----------------
__global__ __launch_bounds__(256) void pool_kernel(const float* __restrict__ x,
                                                   __hip_bfloat16* __restrict__ xap,
                                                   float* __restrict__ wbuf,
                                                   float* __restrict__ gap) {
  __shared__ float sf[4][196];
  int t = threadIdx.x, wid = t >> 6, lane = t & 63;
  int row = blockIdx.x * 4 + wid;  // b*512 + c
  const f32x4* xr = (const f32x4*)(x + (size_t)row * NHW);
  f32x4 v0 = xr[lane];
  f32x4 v1 = xr[lane + 64];
  f32x4 v2 = xr[lane + 128];
  sf[wid][lane] = (v0.x + v0.y) + (v0.z + v0.w);
  sf[wid][lane + 64] = (v1.x + v1.y) + (v1.z + v1.w);
  sf[wid][lane + 128] = (v2.x + v2.y) + (v2.z + v2.w);
  if (lane < 4) {
    f32x4 v3 = xr[lane + 192];
    sf[wid][lane + 192] = (v3.x + v3.y) + (v3.z + v3.w);
  }
  __syncthreads();
  float bin = 0.f;
  if (lane < NK) {
    int pr = lane / 7, pc = lane - pr * 7;
    int f0 = pr * 28 + pc;
    bin = ((sf[wid][f0] + sf[wid][f0 + 7]) + (sf[wid][f0 + 14] + sf[wid][f0 + 21])) * 0.0625f;
  }
  float s1 = wave_sum(bin);
  float s2 = wave_sum(bin * bin);
  xap[(size_t)row * KP + lane] = __float2bfloat16(bin);  // lanes>=49 write 0 pad
  if (lane == 0) {
    wbuf[row] = sqrtf(s2);         // per-channel L2 norm (exact; once per row)
    gap[row] = s1 * (1.f / 49.f);  // == mean over 784
  }
}

// ---------------- K2: pass A — weighted sum of d per (batch, triangle-tile) ----------------
__global__ __launch_bounds__(256) void meand_kernel(const __hip_bfloat16* __restrict__ xap,
                                                    const float* __restrict__ wbuf,
                                                    float* __restrict__ dpart) {
  __shared__ __align__(16) __hip_bfloat16 Ab[128 * KP];
  __shared__ __align__(16) __hip_bfloat16 Bb[128 * KP];
  __shared__ float wiL[128], wjL[128];
  __shared__ float red[4];
  int blk = blockIdx.x;
  int b = blk / NTASK, s = blk - b * NTASK;
  int ti, tj;
  task_decode(s, ti, tj);
  bool diag = (ti == tj);
  int i0 = ti * 128, j0 = tj * 128;
  int t = threadIdx.x;
  const v4i* ga = (const v4i*)(xap + ((size_t)b * NC + i0) * KP);
  const v4i* gb = (const v4i*)(xap + ((size_t)b * NC + j0) * KP);
  v4i* la = (v4i*)Ab;
  v4i* lb = (v4i*)Bb;
#pragma unroll
  for (int q = 0; q < 4; ++q) {
    int cid = q * 256 + t;
    int r = cid >> 3, c = cid & 7;
    int dst = (r << 3) | (c ^ (r & 7));
    la[dst] = ga[cid];
    lb[dst] = gb[cid];
  }
  if (t < 128) {
    wiL[t] = wbuf[b * NC + i0 + t];
    wjL[t] = wbuf[b * NC + j0 + t];
  }
  __syncthreads();
  int lane = t & 63, wave = t >> 6;
  int wi = wave >> 1, wn = wave & 1;
  int l15 = lane & 15, g16 = lane >> 4;
  sh8 af[4][2], bfr[4][2];
#pragma unroll
  for (int f = 0; f < 4; ++f) {
#pragma unroll
    for (int ks = 0; ks < 2; ++ks) {
      int ra = wi * 64 + f * 16 + l15;
      int rb = wn * 64 + f * 16 + l15;
      int cg2 = ks * 4 + g16;
      af[f][ks] = __builtin_bit_cast(sh8, ((const v4i*)Ab)[(ra << 3) | (cg2 ^ (ra & 7))]);
      bfr[f][ks] = __builtin_bit_cast(sh8, ((const v4i*)Bb)[(rb << 3) | (cg2 ^ (rb & 7))]);
    }
  }
  f32x4 acc[4][4];
#pragma unroll
  for (int fm = 0; fm < 4; ++fm)
#pragma unroll
    for (int fn = 0; fn < 4; ++fn) acc[fm][fn] = (f32x4){0.f, 0.f, 0.f, 0.f};
#pragma unroll
  for (int ks = 0; ks < 2; ++ks)
#pragma unroll
    for (int fm = 0; fm < 4; ++fm)
#pragma unroll
      for (int fn = 0; fn < 4; ++fn)
        acc[fm][fn] =
            __builtin_amdgcn_mfma_f32_16x16x32_bf16(af[fm][ks], bfr[fn][ks], acc[fm][fn], 0, 0, 0);
  float a2[4][4], b2[4];
#pragma unroll
  for (int fm = 0; fm < 4; ++fm)
#pragma unroll
    for (int rg = 0; rg < 4; ++rg) {
      float a = wiL[wi * 64 + fm * 16 + g16 * 4 + rg];
      a2[fm][rg] = a * a;
    }
#pragma unroll
  for (int fn = 0; fn < 4; ++fn) {
    float w = wjL[wn * 64 + fn * 16 + l15];
    b2[fn] = w * w;
  }
  float dsum = 0.f;
#pragma unroll
  for (int fm = 0; fm < 4; ++fm)
#pragma unroll
    for (int fn = 0; fn < 4; ++fn)
#pragma unroll
      for (int rg = 0; rg < 4; ++rg) {
        float d2 = fmaf(-2.f, acc[fm][fn][rg], a2[fm][rg] + b2[fn]);
        dsum += __builtin_amdgcn_sqrtf(fmaxf(d2, 0.f));  // HW sqrt (1 inst)
      }
  dsum = wave_sum(dsum);
  if (lane == 0) red[wave] = dsum;
  __syncthreads();
  if (t == 0) dpart[blk] = ((red[0] + red[1]) + (red[2] + red[3])) * (diag ? 1.f : 2.f);
}

// ---------------- K3: pass B — sim on triangle tiles; rows AND cols of t; weighted S ----
__global__ __launch_bounds__(256) void sim_kernel(const __hip_bfloat16* __restrict__ xap,
                                                  const float* __restrict__ wbuf,
                                                  const float* __restrict__ gap,
                                                  const float* __restrict__ dpart,
                                                  float* __restrict__ tpart,
                                                  float* __restrict__ spart) {
  __shared__ __align__(16) __hip_bfloat16 Ab[128 * KP];
  __shared__ __align__(16) __hip_bfloat16 Bb[128 * KP];
  __shared__ float wiL[128], wjL[128], zL[NC], tfull[NC];
  __shared__ float red[4];
  int blk = blockIdx.x;
  int b = blk / NTASK, s = blk - b * NTASK;
  int ti, tj;
  task_decode(s, ti, tj);
  bool diag = (ti == tj);
  int i0 = ti * 128, j0 = tj * 128;
  int t = threadIdx.x;
  int lane = t & 63, wave = t >> 6;
  float dsb = 0.f;
#pragma unroll
  for (int k = 0; k < NTASK; ++k) dsb += dpart[b * NTASK + k];
  float nim = -1.f / (dsb * (1.f / 262144.f) + 1e-10f);  // -1/mean_d (exact, once)
  const v4i* ga = (const v4i*)(xap + ((size_t)b * NC + i0) * KP);
  const v4i* gb = (const v4i*)(xap + ((size_t)b * NC + j0) * KP);
  v4i* la = (v4i*)Ab;
  v4i* lb = (v4i*)Bb;
#pragma unroll
  for (int q = 0; q < 4; ++q) {
    int cid = q * 256 + t;
    int r = cid >> 3, c = cid & 7;
    int dst = (r << 3) | (c ^ (r & 7));
    la[dst] = ga[cid];
    lb[dst] = gb[cid];
  }
  if (t < 128) {
    wiL[t] = wbuf[b * NC + i0 + t];
    wjL[t] = wbuf[b * NC + j0 + t];
  }
  tfull[t] = 0.f;
  tfull[t + 256] = 0.f;
  // z = (gap - mu)/std (unbiased) — identical expression in mlp_kernel (bitwise match)
  float g0 = gap[b * NC + t], g1 = gap[b * NC + t + 256];
  float s1 = wave_sum(g0 + g1);
  if (lane == 0) red[wave] = s1;
  __syncthreads();
  float mu = ((red[0] + red[1]) + (red[2] + red[3])) * (1.f / 512.f);
  float e0 = g0 - mu, e1 = g1 - mu;
  __syncthreads();
  float vv = wave_sum(e0 * e0 + e1 * e1);
  if (lane == 0) red[wave] = vv;
  __syncthreads();
  float inv_sd = __builtin_amdgcn_rsqf(((red[0] + red[1]) + (red[2] + red[3])) * (1.f / 511.f));
  zL[t] = e0 * inv_sd;
  zL[t + 256] = e1 * inv_sd;
  __syncthreads();
  int wi = wave >> 1, wn = wave & 1;
  int l15 = lane & 15, g16 = lane >> 4;
  sh8 af[4][2], bfr[4][2];
#pragma unroll
  for (int f = 0; f < 4; ++f) {
#pragma unroll
    for (int ks = 0; ks < 2; ++ks) {
      int ra = wi * 64 + f * 16 + l15;
      int rb = wn * 64 + f * 16 + l15;
      int cg2 = ks * 4 + g16;
      af[f][ks] = __builtin_bit_cast(sh8, ((const v4i*)Ab)[(ra << 3) | (cg2 ^ (ra & 7))]);
      bfr[f][ks] = __builtin_bit_cast(sh8, ((const v4i*)Bb)[(rb << 3) | (cg2 ^ (rb & 7))]);
    }
  }
  f32x4 acc[4][4];
#pragma unroll
  for (int fm = 0; fm < 4; ++fm)
#pragma unroll
    for (int fn = 0; fn < 4; ++fn) acc[fm][fn] = (f32x4){0.f, 0.f, 0.f, 0.f};
#pragma unroll
  for (int ks = 0; ks < 2; ++ks)
#pragma unroll
    for (int fm = 0; fm < 4; ++fm)
#pragma unroll
      for (int fn = 0; fn < 4; ++fn)
        acc[fm][fn] =
            __builtin_amdgcn_mfma_f32_16x16x32_bf16(af[fm][ks], bfr[fn][ks], acc[fm][fn], 0, 0, 0);
  float a2[4][4], ia[4][4], zi[4][4];
#pragma unroll
  for (int fm = 0; fm < 4; ++fm)
#pragma unroll
    for (int rg = 0; rg < 4; ++rg) {
      int il = wi * 64 + fm * 16 + g16 * 4 + rg;
      float a = wiL[il];
      a2[fm][rg] = a * a;
      ia[fm][rg] = __builtin_amdgcn_rcpf(fmaxf(a, 1e-7f));  // HW rcp
      zi[fm][rg] = zL[i0 + il];
    }
  float b2[4], ib[4], zj[4];
#pragma unroll
  for (int fn = 0; fn < 4; ++fn) {
    int jl = wn * 64 + fn * 16 + l15;
    float w = wjL[jl];
    b2[fn] = w * w;
    ib[fn] = __builtin_amdgcn_rcpf(fmaxf(w, 1e-7f));
    zj[fn] = zL[j0 + jl];
  }
  float ssum = 0.f;
  float trow[4][4];
  float tcol[4] = {0.f, 0.f, 0.f, 0.f};
#pragma unroll
  for (int fm = 0; fm < 4; ++fm)
#pragma unroll
    for (int rg = 0; rg < 4; ++rg) trow[fm][rg] = 0.f;
#pragma unroll
  for (int fm = 0; fm < 4; ++fm)
#pragma unroll
    for (int fn = 0; fn < 4; ++fn) {
      float ibn = ib[fn];
#pragma unroll
      for (int rg = 0; rg < 4; ++rg) {
        float g = acc[fm][fn][rg];
        float d2 = fmaf(-2.f, g, a2[fm][rg] + b2[fn]);
        float d = __builtin_amdgcn_sqrtf(fmaxf(d2, 0.f));
        float sim = fmaxf(g, 0.f) * ia[fm][rg] * ibn * __expf(d * nim);
        if (diag) {
          int il = wi * 64 + fm * 16 + g16 * 4 + rg;
          int jl = wn * 64 + fn * 16 + l15;
          if (il == jl) sim = 0.f;
        }
        ssum += sim;
        trow[fm][rg] = fmaf(sim, zj[fn], trow[fm][rg]);
        tcol[fn] = fmaf(sim, zi[fm][rg], tcol[fn]);
      }
    }
  // row contributions: reduce over l15 (j within 16-group)
#pragma unroll
  for (int fm = 0; fm < 4; ++fm)
#pragma unroll
    for (int rg = 0; rg < 4; ++rg) {
      float v = trow[fm][rg];
#pragma unroll
      for (int o = 8; o; o >>= 1) v += __shfl_xor(v, o);
      if (l15 == 0) atomicAdd(&tfull[i0 + wi * 64 + fm * 16 + g16 * 4 + rg], v);
    }
  // column contributions (off-diag tiles only)
  if (!diag) {
#pragma unroll
    for (int fn = 0; fn < 4; ++fn) {
      float v = tcol[fn];
      v += __shfl_xor(v, 16);
      v += __shfl_xor(v, 32);
      if (g16 == 0) atomicAdd(&tfull[j0 + wn * 64 + fn * 16 + l15], v);
    }
  }
  ssum = wave_sum(ssum);
  if (lane == 0) red[wave] = ssum;
  __syncthreads();
  if (t == 0) spart[blk] = ((red[0] + red[1]) + (red[2] + red[3])) * (diag ? 1.f : 2.f);
  tpart[(size_t)blk * NC + t] = tfull[t];
  tpart[(size_t)blk * NC + t + 256] = tfull[t + 256];
}

// ---------------- K4: per-batch z, local_mi -> normalize -> MLP -> sigmoid scale ----------
__global__ __launch_bounds__(256) void mlp_kernel(const float* __restrict__ gap,
                                                  const float* __restrict__ tpart,
                                                  const float* __restrict__ spart,
                                                  const float* __restrict__ wD,
                                                  const float* __restrict__ bD,
                                                  const float* __restrict__ wU,
                                                  const float* __restrict__ bU,
                                                  float* __restrict__ scl) {
  __shared__ float red[4];
  __shared__ float chL[NC];
  __shared__ float hL[NR];
  int b = blockIdx.x, t = threadIdx.x;
  int lane = t & 63, wid = t >> 6;
  float S = 0.f;
#pragma unroll
  for (int k = 0; k < NTASK; ++k) S += spart[b * NTASK + k];
  float invS = 1.f / (S + 1e-10f);  // once
  float t0 = 0.f, t1 = 0.f;
#pragma unroll
  for (int j = 0; j < NTASK; ++j) {
    t0 += tpart[((size_t)b * NTASK + j) * NC + t];
    t1 += tpart[((size_t)b * NTASK + j) * NC + t + 256];
  }
  // z from gap (identical arithmetic to sim_kernel)
  float g0 = gap[b * NC + t], g1 = gap[b * NC + t + 256];
  float s1 = wave_sum(g0 + g1);
  if (lane == 0) red[wid] = s1;
  __syncthreads();
  float mu = ((red[0] + red[1]) + (red[2] + red[3])) * (1.f / 512.f);
  float e0 = g0 - mu, e1 = g1 - mu;
  __syncthreads();
  float vv = wave_sum(e0 * e0 + e1 * e1);
  if (lane == 0) red[wid] = vv;
  __syncthreads();
  float inv_sd = __builtin_amdgcn_rsqf(((red[0] + red[1]) + (red[2] + red[3])) * (1.f / 511.f));
  float lm0 = e0 * inv_sd * t0 * invS;
  float lm1 = e1 * inv_sd * t1 * invS;
  __syncthreads();
  float s2 = wave_sum(lm0 + lm1);
  if (lane == 0) red[wid] = s2;
  __syncthreads();
  float m = ((red[0] + red[1]) + (red[2] + red[3])) * (1.f / 512.f);
  float d0 = lm0 - m, d1 = lm1 - m;
  __syncthreads();
  float v2 = wave_sum(d0 * d0 + d1 * d1);
  if (lane == 0) red[wid] = v2;
  __syncthreads();
  float isd2 = __builtin_amdgcn_rcpf(
      sqrtf(((red[0] + red[1]) + (red[2] + red[3])) * (1.f / 511.f)) + 1e-12f);
  chL[t] = d0 * isd2;
  chL[t + 256] = d1 * isd2;
  __syncthreads();
  int k = t >> 3, p = t & 7;
  const float* wrow = wD + k * NC + p * 64;
  const float* cp = chL + p * 64;
  float hp = 0.f;
#pragma unroll
  for (int i = 0; i < 64; ++i) hp += wrow[i] * cp[i];
#pragma unroll
  for (int o = 4; o; o >>= 1) hp += __shfl_xor(hp, o);
  if (p == 0) hL[k] = fmaxf(hp + bD[k], 0.f);
  __syncthreads();
#pragma unroll
  for (int u = 0; u < 2; ++u) {
    int c = t + u * 256;
    const float* wrU = wU + c * NR;
    float att = bU[c];
#pragma unroll
    for (int kk = 0; kk < NR; ++kk) att += hL[kk] * wrU[kk];
    scl[b * NC + c] = __builtin_amdgcn_rcpf(1.f + __expf(-att));
  }
}

// ---------------- K5: out = x * scale (x from L3; NT store for out) ----------------
__global__ __launch_bounds__(256) void scale_kernel(const float* __restrict__ x,
                                                    const float* __restrict__ scl,
                                                    float* __restrict__ out) {
  unsigned idx = blockIdx.x * 256u + threadIdx.x;  // float4 index, total 6422528
  unsigned row = idx / 196u;                       // b*512 + c
  float s = scl[row];
  f32x4 v = ((const f32x4*)x)[idx];
  v *= s;
  __builtin_nontemporal_store(v, ((f32x4*)out) + idx);
}

extern "C" void kernel_launch(void* const* d_in, const int* in_sizes, int n_in,
                              void* d_out, int out_size, void* d_ws, size_t ws_size,
                              hipStream_t stream) {
  const float* x = (const float*)d_in[0];
  const float* wD = (const float*)d_in[1];
  const float* bD = (const float*)d_in[2];
  const float* wU = (const float*)d_in[3];
  const float* bU = (const float*)d_in[4];
  float* out = (float*)d_out;
  char* ws = (char*)d_ws;

  __hip_bfloat16* xap = (__hip_bfloat16*)ws;  // 64*512*64*2 = 4 MB
  float* fbase = (float*)(ws + (size_t)NB * NC * KP * 2);
  float* wbuf = fbase;                   // 32768 f32
  float* gap = wbuf + NB * NC;           // 32768
  float* dpart = gap + NB * NC;          // 640
  float* spart = dpart + NB * NTASK;     // 640
  float* tpart = spart + NB * NTASK;     // 64*10*512 = 327680
  float* scl = tpart + NB * NTASK * NC;  // 32768

  hipLaunchKernelGGL(pool_kernel, dim3(NB * NC / 4), dim3(256), 0, stream, x, xap, wbuf, gap);
  hipLaunchKernelGGL(meand_kernel, dim3(NB * NTASK), dim3(256), 0, stream, xap, wbuf, dpart);
  hipLaunchKernelGGL(sim_kernel, dim3(NB * NTASK), dim3(256), 0, stream, xap, wbuf, gap, dpart,
                     tpart, spart);
  hipLaunchKernelGGL(mlp_kernel, dim3(NB), dim3(256), 0, stream, gap, tpart, spart, wD, bD, wU, bU,
                     scl);
  hipLaunchKernelGGL(scale_kernel, dim3(25088), dim3(256), 0, stream, x, scl, out);
}